// Round 1
// baseline (586.508 us; speedup 1.0000x reference)
//
#include <hip/hip_runtime.h>
#include <math.h>

#define N_NODES 50000
#define N_EDGES 800000
#define IN_FEATS 128
#define N_HIDDEN 128
#define N_CLASSES 40
#define SEQ_LEN 20

// ---------------- workspace layout (bytes, 256-aligned) ----------------
// out_cnt : 0         int[50000]
// in_cnt  : 200192    int[50000]
// csc_off : 400384    int[50001]
// cursor  : 600576    int[50000]
// csc_src : 800768    int[800000]
// hA      : 4000768   float[50000*128]   (h0, then h1)
// hB      : 29600768  float[50000*128]   (G1, then G2)
// total ~55.2 MB

__global__ void zero_ints(int* __restrict__ p, int n) {
    int i = blockIdx.x * blockDim.x + threadIdx.x;
    if (i < n) p[i] = 0;
}

__global__ void degree_kernel(const int* __restrict__ src, const int* __restrict__ dst,
                              int* __restrict__ out_cnt, int* __restrict__ in_cnt, int n_edges) {
    int e = blockIdx.x * blockDim.x + threadIdx.x;
    if (e < n_edges) {
        atomicAdd(&out_cnt[src[e]], 1);
        atomicAdd(&in_cnt[dst[e]], 1);
    }
}

// exclusive scan of in_cnt -> csc_off (and cursor copy); single block of 1024
__global__ __launch_bounds__(1024) void scan_kernel(const int* __restrict__ in_cnt,
                                                    int* __restrict__ csc_off,
                                                    int* __restrict__ cursor, int n) {
    __shared__ int part[1024];
    int t = threadIdx.x;
    int chunk = (n + 1023) >> 10;            // 49 for n=50000
    int lo = t * chunk;
    int hi = min(lo + chunk, n);
    int s = 0;
    for (int i = lo; i < hi; ++i) s += in_cnt[i];
    part[t] = s;
    __syncthreads();
    // Hillis-Steele inclusive scan
    for (int d = 1; d < 1024; d <<= 1) {
        int v = (t >= d) ? part[t - d] : 0;
        __syncthreads();
        part[t] += v;
        __syncthreads();
    }
    int run = (t == 0) ? 0 : part[t - 1];    // exclusive prefix of this chunk
    for (int i = lo; i < hi; ++i) {
        csc_off[i] = run;
        cursor[i] = run;
        run += in_cnt[i];
    }
    if (t == 1023) csc_off[n] = run;         // t=1023's range is empty -> run == grand total
}

__global__ void fill_csc(const int* __restrict__ src, const int* __restrict__ dst,
                         int* __restrict__ cursor, int* __restrict__ csc_src, int n_edges) {
    int e = blockIdx.x * blockDim.x + threadIdx.x;
    if (e < n_edges) {
        int p = atomicAdd(&cursor[dst[e]], 1);
        csc_src[p] = src[e];
    }
}

// embedding mean-pool + fold in rsqrt(out_deg) scaling for layer-1 GEMM input
__global__ void pool_kernel(const int* __restrict__ feats, const float* __restrict__ emb,
                            const int* __restrict__ out_cnt, float* __restrict__ h0) {
    int v = blockIdx.x;
    int f = threadIdx.x;
    const int* tk = feats + v * SEQ_LEN;
    float acc = 0.f;
    int cnt = 0;
    #pragma unroll
    for (int t = 0; t < SEQ_LEN; ++t) {
        int tok = tk[t];
        cnt += (tok != 0);
        acc += emb[tok * IN_FEATS + f];       // pad row 0 is all-zero, safe to sum
    }
    float rout = 1.f / sqrtf(fmaxf((float)out_cnt[v], 1.f));
    float scale = rout / (float)max(cnt, 1);
    h0[v * IN_FEATS + f] = acc * scale;
}

// C[M,128] = A[M,128] @ W[128,128]; 64x64 tile, 256 threads, 4x4/thread
__global__ __launch_bounds__(256) void gemm1_kernel(const float* __restrict__ A,
                                                    const float* __restrict__ W,
                                                    float* __restrict__ C, int M) {
    __shared__ __align__(16) float As[64][132];   // r-major, stride 132 (16B-aligned, conflict-free)
    __shared__ __align__(16) float Bs[128][64];   // k-major
    const int t = threadIdx.x;
    const int row0 = blockIdx.x * 64;
    const int col0 = blockIdx.y * 64;
    #pragma unroll 8
    for (int i = 0; i < 32; ++i) {
        int idx = i * 256 + t;
        int r = idx >> 7, k = idx & 127;
        int row = row0 + r;
        As[r][k] = (row < M) ? A[row * 128 + k] : 0.f;
    }
    #pragma unroll 8
    for (int i = 0; i < 32; ++i) {
        int idx = i * 256 + t;
        int k = idx >> 6, c = idx & 63;
        Bs[k][c] = W[k * 128 + col0 + c];
    }
    __syncthreads();
    const int cg = t & 15, rg = t >> 4;
    float acc[4][4] = {};
    for (int k = 0; k < 128; k += 4) {
        float4 a0 = *(const float4*)&As[rg * 4 + 0][k];
        float4 a1 = *(const float4*)&As[rg * 4 + 1][k];
        float4 a2 = *(const float4*)&As[rg * 4 + 2][k];
        float4 a3 = *(const float4*)&As[rg * 4 + 3][k];
        float4 b0 = *(const float4*)&Bs[k + 0][cg * 4];
        float4 b1 = *(const float4*)&Bs[k + 1][cg * 4];
        float4 b2 = *(const float4*)&Bs[k + 2][cg * 4];
        float4 b3 = *(const float4*)&Bs[k + 3][cg * 4];
        float av[4][4] = {{a0.x, a0.y, a0.z, a0.w}, {a1.x, a1.y, a1.z, a1.w},
                          {a2.x, a2.y, a2.z, a2.w}, {a3.x, a3.y, a3.z, a3.w}};
        float bv[4][4] = {{b0.x, b0.y, b0.z, b0.w}, {b1.x, b1.y, b1.z, b1.w},
                          {b2.x, b2.y, b2.z, b2.w}, {b3.x, b3.y, b3.z, b3.w}};
        #pragma unroll
        for (int i = 0; i < 4; ++i)
            #pragma unroll
            for (int kk = 0; kk < 4; ++kk)
                #pragma unroll
                for (int j = 0; j < 4; ++j)
                    acc[i][j] += av[i][kk] * bv[kk][j];
    }
    #pragma unroll
    for (int i = 0; i < 4; ++i) {
        int row = row0 + rg * 4 + i;
        if (row < M) {
            float4 o = {acc[i][0], acc[i][1], acc[i][2], acc[i][3]};
            *(float4*)&C[row * 128 + col0 + cg * 4] = o;
        }
    }
}

// C[M,40] = A[M,128] @ W[128,40]; 64-row tile, 256 threads, cg<10 active
__global__ __launch_bounds__(256) void gemm2_kernel(const float* __restrict__ A,
                                                    const float* __restrict__ W,
                                                    float* __restrict__ C, int M) {
    __shared__ __align__(16) float As[64][132];
    __shared__ __align__(16) float Bs[128 * 40];
    const int t = threadIdx.x;
    const int row0 = blockIdx.x * 64;
    #pragma unroll 8
    for (int i = 0; i < 32; ++i) {
        int idx = i * 256 + t;
        int r = idx >> 7, k = idx & 127;
        int row = row0 + r;
        As[r][k] = (row < M) ? A[row * 128 + k] : 0.f;
    }
    for (int idx = t; idx < 128 * 40; idx += 256) Bs[idx] = W[idx];
    __syncthreads();
    const int cg = t & 15, rg = t >> 4;
    float acc[4][4] = {};
    if (cg < 10) {
        for (int k = 0; k < 128; k += 4) {
            float4 a0 = *(const float4*)&As[rg * 4 + 0][k];
            float4 a1 = *(const float4*)&As[rg * 4 + 1][k];
            float4 a2 = *(const float4*)&As[rg * 4 + 2][k];
            float4 a3 = *(const float4*)&As[rg * 4 + 3][k];
            float4 b0 = *(const float4*)&Bs[(k + 0) * 40 + cg * 4];
            float4 b1 = *(const float4*)&Bs[(k + 1) * 40 + cg * 4];
            float4 b2 = *(const float4*)&Bs[(k + 2) * 40 + cg * 4];
            float4 b3 = *(const float4*)&Bs[(k + 3) * 40 + cg * 4];
            float av[4][4] = {{a0.x, a0.y, a0.z, a0.w}, {a1.x, a1.y, a1.z, a1.w},
                              {a2.x, a2.y, a2.z, a2.w}, {a3.x, a3.y, a3.z, a3.w}};
            float bv[4][4] = {{b0.x, b0.y, b0.z, b0.w}, {b1.x, b1.y, b1.z, b1.w},
                              {b2.x, b2.y, b2.z, b2.w}, {b3.x, b3.y, b3.z, b3.w}};
            #pragma unroll
            for (int i = 0; i < 4; ++i)
                #pragma unroll
                for (int kk = 0; kk < 4; ++kk)
                    #pragma unroll
                    for (int j = 0; j < 4; ++j)
                        acc[i][j] += av[i][kk] * bv[kk][j];
        }
        #pragma unroll
        for (int i = 0; i < 4; ++i) {
            int row = row0 + rg * 4 + i;
            if (row < M) {
                float4 o = {acc[i][0], acc[i][1], acc[i][2], acc[i][3]};
                *(float4*)&C[row * 40 + cg * 4] = o;
            }
        }
    }
}

// layer-1 aggregate + epilogue: h1 = relu(sum*rin + b1) * rout   (width 128)
__global__ void spmm1_kernel(const int* __restrict__ csc_off, const int* __restrict__ csc_src,
                             const int* __restrict__ out_cnt, const float* __restrict__ G,
                             const float* __restrict__ b1, float* __restrict__ H) {
    int v = blockIdx.x;
    int f = threadIdx.x;
    int beg = csc_off[v], end = csc_off[v + 1];
    float acc = 0.f;
    for (int e = beg; e < end; ++e) {
        int u = csc_src[e];
        acc += G[u * 128 + f];
    }
    float rin = 1.f / sqrtf(fmaxf((float)(end - beg), 1.f));
    float rout = 1.f / sqrtf(fmaxf((float)out_cnt[v], 1.f));
    float x = acc * rin + b1[f];
    H[v * 128 + f] = fmaxf(x, 0.f) * rout;
}

// layer-2 aggregate + epilogue: out = sum*rin + b2   (width 40)
__global__ void spmm2_kernel(const int* __restrict__ csc_off, const int* __restrict__ csc_src,
                             const float* __restrict__ G2, const float* __restrict__ b2,
                             float* __restrict__ out) {
    int v = blockIdx.x;
    int f = threadIdx.x;
    int beg = csc_off[v], end = csc_off[v + 1];
    if (f < N_CLASSES) {
        float acc = 0.f;
        for (int e = beg; e < end; ++e) acc += G2[csc_src[e] * N_CLASSES + f];
        float rin = 1.f / sqrtf(fmaxf((float)(end - beg), 1.f));
        out[v * N_CLASSES + f] = acc * rin + b2[f];
    }
}

extern "C" void kernel_launch(void* const* d_in, const int* in_sizes, int n_in,
                              void* d_out, int out_size, void* d_ws, size_t ws_size,
                              hipStream_t stream) {
    const int*   feats = (const int*)d_in[0];
    const int*   src   = (const int*)d_in[1];
    const int*   dst   = (const int*)d_in[2];
    const float* emb   = (const float*)d_in[3];
    const float* W1    = (const float*)d_in[4];
    const float* b1    = (const float*)d_in[5];
    const float* W2    = (const float*)d_in[6];
    const float* b2    = (const float*)d_in[7];
    float* out = (float*)d_out;

    char* w = (char*)d_ws;
    int*   out_cnt = (int*)(w + 0);
    int*   in_cnt  = (int*)(w + 200192);
    int*   csc_off = (int*)(w + 400384);
    int*   cursor  = (int*)(w + 600576);
    int*   csc_src = (int*)(w + 800768);
    float* hA      = (float*)(w + 4000768);
    float* hB      = (float*)(w + 29600768);

    // 1) zero degree counters (covers out_cnt + in_cnt region)
    zero_ints<<<(100096 + 255) / 256, 256, 0, stream>>>((int*)w, 100096);
    // 2) degree histograms
    degree_kernel<<<(N_EDGES + 255) / 256, 256, 0, stream>>>(src, dst, out_cnt, in_cnt, N_EDGES);
    // 3) exclusive scan -> CSC offsets (+cursor)
    scan_kernel<<<1, 1024, 0, stream>>>(in_cnt, csc_off, cursor, N_NODES);
    // 4) CSC fill (counting-sort placement)
    fill_csc<<<(N_EDGES + 255) / 256, 256, 0, stream>>>(src, dst, cursor, csc_src, N_EDGES);
    // 5) embedding mean-pool (+rsqrt(out_deg) fold) -> hA = h0_scaled
    pool_kernel<<<N_NODES, 128, 0, stream>>>(feats, emb, out_cnt, hA);
    // 6) G1 = h0_scaled @ W1 -> hB
    gemm1_kernel<<<dim3((N_NODES + 63) / 64, 2), 256, 0, stream>>>(hA, W1, hB, N_NODES);
    // 7) h1 = relu(agg(G1)*rin + b1)*rout -> hA
    spmm1_kernel<<<N_NODES, 128, 0, stream>>>(csc_off, csc_src, out_cnt, hB, b1, hA);
    // 8) G2 = h1 @ W2 -> hB
    gemm2_kernel<<<(N_NODES + 63) / 64, 256, 0, stream>>>(hA, W2, hB, N_NODES);
    // 9) out = agg(G2)*rin + b2
    spmm2_kernel<<<N_NODES, 64, 0, stream>>>(csc_off, csc_src, hB, b2, out);
}

// Round 2
// 486.381 us; speedup vs baseline: 1.2059x; 1.2059x over previous
//
#include <hip/hip_runtime.h>
#include <math.h>

#define N_NODES 50000
#define N_EDGES 800000
#define IN_FEATS 128
#define N_HIDDEN 128
#define N_CLASSES 40
#define SEQ_LEN 20
#define SCAN_BLOCKS 196   // ceil(50000/256)

// ---------------- workspace layout (bytes, 256-aligned) ----------------
// out_cnt : 0         int[50000]
// in_cnt  : 200192    int[50000]
// csc_off : 400384    int[50001]
// cursor  : 600576    int[50000]
// csc_src : 800768    int[800000]
// partials: 4000768   int[256]  (reuse area before hA? no - put at 4000768- )
// hA      : 4096000   float[50000*128]
// hB      : 29696000  float[50000*128]
// total ~55.3 MB

__global__ void zero_ints(int* __restrict__ p, int n) {
    int i = blockIdx.x * blockDim.x + threadIdx.x;
    if (i < n) p[i] = 0;
}

__global__ void degree_kernel(const int* __restrict__ src, const int* __restrict__ dst,
                              int* __restrict__ out_cnt, int* __restrict__ in_cnt, int n_edges) {
    int e = blockIdx.x * blockDim.x + threadIdx.x;
    if (e < n_edges) {
        atomicAdd(&out_cnt[src[e]], 1);
        atomicAdd(&in_cnt[dst[e]], 1);
    }
}

// ---- 3-phase exclusive scan of in_cnt[50000] -> csc_off / cursor ----
__global__ __launch_bounds__(256) void part_sums(const int* __restrict__ in_cnt,
                                                 int* __restrict__ partials) {
    __shared__ int s[256];
    int t = threadIdx.x;
    int i = blockIdx.x * 256 + t;
    s[t] = (i < N_NODES) ? in_cnt[i] : 0;
    __syncthreads();
    #pragma unroll
    for (int d = 128; d > 0; d >>= 1) {
        if (t < d) s[t] += s[t + d];
        __syncthreads();
    }
    if (t == 0) partials[blockIdx.x] = s[0];
}

__global__ __launch_bounds__(256) void scan_partials(const int* __restrict__ partials,
                                                     int* __restrict__ block_off,
                                                     int* __restrict__ csc_off) {
    __shared__ int s[256];
    int t = threadIdx.x;
    int v = (t < SCAN_BLOCKS) ? partials[t] : 0;
    s[t] = v;
    __syncthreads();
    #pragma unroll
    for (int d = 1; d < 256; d <<= 1) {
        int x = (t >= d) ? s[t - d] : 0;
        __syncthreads();
        s[t] += x;
        __syncthreads();
    }
    block_off[t] = s[t] - v;                  // exclusive
    if (t == 255) csc_off[N_NODES] = s[255];  // grand total
}

__global__ __launch_bounds__(256) void apply_scan(const int* __restrict__ in_cnt,
                                                  const int* __restrict__ block_off,
                                                  int* __restrict__ csc_off,
                                                  int* __restrict__ cursor) {
    __shared__ int s[256];
    int t = threadIdx.x;
    int i = blockIdx.x * 256 + t;
    int v = (i < N_NODES) ? in_cnt[i] : 0;
    s[t] = v;
    __syncthreads();
    #pragma unroll
    for (int d = 1; d < 256; d <<= 1) {
        int x = (t >= d) ? s[t - d] : 0;
        __syncthreads();
        s[t] += x;
        __syncthreads();
    }
    if (i < N_NODES) {
        int o = block_off[blockIdx.x] + s[t] - v;
        csc_off[i] = o;
        cursor[i] = o;
    }
}

__global__ void fill_csc(const int* __restrict__ src, const int* __restrict__ dst,
                         int* __restrict__ cursor, int* __restrict__ csc_src, int n_edges) {
    int e = blockIdx.x * blockDim.x + threadIdx.x;
    if (e < n_edges) {
        int p = atomicAdd(&cursor[dst[e]], 1);
        csc_src[p] = src[e];
    }
}

// embedding mean-pool + fold in rsqrt(out_deg) scaling for layer-1 GEMM input
__global__ void pool_kernel(const int* __restrict__ feats, const float* __restrict__ emb,
                            const int* __restrict__ out_cnt, float* __restrict__ h0) {
    int v = blockIdx.x;
    int f = threadIdx.x;
    const int* tk = feats + v * SEQ_LEN;
    float acc = 0.f;
    int cnt = 0;
    #pragma unroll
    for (int t = 0; t < SEQ_LEN; ++t) {
        int tok = tk[t];
        cnt += (tok != 0);
        acc += emb[tok * IN_FEATS + f];       // pad row 0 is all-zero, safe to sum
    }
    float rout = 1.f / sqrtf(fmaxf((float)out_cnt[v], 1.f));
    float scale = rout / (float)max(cnt, 1);
    h0[v * IN_FEATS + f] = acc * scale;
}

// C[M,128] = A[M,128] @ W[128,128]; 64x64 tile, 256 threads, 4x4/thread
__global__ __launch_bounds__(256) void gemm1_kernel(const float* __restrict__ A,
                                                    const float* __restrict__ W,
                                                    float* __restrict__ C, int M) {
    __shared__ __align__(16) float As[64][132];
    __shared__ __align__(16) float Bs[128][64];
    const int t = threadIdx.x;
    const int row0 = blockIdx.x * 64;
    const int col0 = blockIdx.y * 64;
    #pragma unroll 8
    for (int i = 0; i < 32; ++i) {
        int idx = i * 256 + t;
        int r = idx >> 7, k = idx & 127;
        int row = row0 + r;
        As[r][k] = (row < M) ? A[row * 128 + k] : 0.f;
    }
    #pragma unroll 8
    for (int i = 0; i < 32; ++i) {
        int idx = i * 256 + t;
        int k = idx >> 6, c = idx & 63;
        Bs[k][c] = W[k * 128 + col0 + c];
    }
    __syncthreads();
    const int cg = t & 15, rg = t >> 4;
    float acc[4][4] = {};
    for (int k = 0; k < 128; k += 4) {
        float4 a0 = *(const float4*)&As[rg * 4 + 0][k];
        float4 a1 = *(const float4*)&As[rg * 4 + 1][k];
        float4 a2 = *(const float4*)&As[rg * 4 + 2][k];
        float4 a3 = *(const float4*)&As[rg * 4 + 3][k];
        float4 b0 = *(const float4*)&Bs[k + 0][cg * 4];
        float4 b1 = *(const float4*)&Bs[k + 1][cg * 4];
        float4 b2 = *(const float4*)&Bs[k + 2][cg * 4];
        float4 b3 = *(const float4*)&Bs[k + 3][cg * 4];
        float av[4][4] = {{a0.x, a0.y, a0.z, a0.w}, {a1.x, a1.y, a1.z, a1.w},
                          {a2.x, a2.y, a2.z, a2.w}, {a3.x, a3.y, a3.z, a3.w}};
        float bv[4][4] = {{b0.x, b0.y, b0.z, b0.w}, {b1.x, b1.y, b1.z, b1.w},
                          {b2.x, b2.y, b2.z, b2.w}, {b3.x, b3.y, b3.z, b3.w}};
        #pragma unroll
        for (int i = 0; i < 4; ++i)
            #pragma unroll
            for (int kk = 0; kk < 4; ++kk)
                #pragma unroll
                for (int j = 0; j < 4; ++j)
                    acc[i][j] += av[i][kk] * bv[kk][j];
    }
    #pragma unroll
    for (int i = 0; i < 4; ++i) {
        int row = row0 + rg * 4 + i;
        if (row < M) {
            float4 o = {acc[i][0], acc[i][1], acc[i][2], acc[i][3]};
            *(float4*)&C[row * 128 + col0 + cg * 4] = o;
        }
    }
}

// C[M,40] = A[M,128] @ W[128,40]; 64-row tile, 256 threads, cg<10 active
__global__ __launch_bounds__(256) void gemm2_kernel(const float* __restrict__ A,
                                                    const float* __restrict__ W,
                                                    float* __restrict__ C, int M) {
    __shared__ __align__(16) float As[64][132];
    __shared__ __align__(16) float Bs[128 * 40];
    const int t = threadIdx.x;
    const int row0 = blockIdx.x * 64;
    #pragma unroll 8
    for (int i = 0; i < 32; ++i) {
        int idx = i * 256 + t;
        int r = idx >> 7, k = idx & 127;
        int row = row0 + r;
        As[r][k] = (row < M) ? A[row * 128 + k] : 0.f;
    }
    for (int idx = t; idx < 128 * 40; idx += 256) Bs[idx] = W[idx];
    __syncthreads();
    const int cg = t & 15, rg = t >> 4;
    float acc[4][4] = {};
    if (cg < 10) {
        for (int k = 0; k < 128; k += 4) {
            float4 a0 = *(const float4*)&As[rg * 4 + 0][k];
            float4 a1 = *(const float4*)&As[rg * 4 + 1][k];
            float4 a2 = *(const float4*)&As[rg * 4 + 2][k];
            float4 a3 = *(const float4*)&As[rg * 4 + 3][k];
            float4 b0 = *(const float4*)&Bs[(k + 0) * 40 + cg * 4];
            float4 b1 = *(const float4*)&Bs[(k + 1) * 40 + cg * 4];
            float4 b2 = *(const float4*)&Bs[(k + 2) * 40 + cg * 4];
            float4 b3 = *(const float4*)&Bs[(k + 3) * 40 + cg * 4];
            float av[4][4] = {{a0.x, a0.y, a0.z, a0.w}, {a1.x, a1.y, a1.z, a1.w},
                              {a2.x, a2.y, a2.z, a2.w}, {a3.x, a3.y, a3.z, a3.w}};
            float bv[4][4] = {{b0.x, b0.y, b0.z, b0.w}, {b1.x, b1.y, b1.z, b1.w},
                              {b2.x, b2.y, b2.z, b2.w}, {b3.x, b3.y, b3.z, b3.w}};
            #pragma unroll
            for (int i = 0; i < 4; ++i)
                #pragma unroll
                for (int kk = 0; kk < 4; ++kk)
                    #pragma unroll
                    for (int j = 0; j < 4; ++j)
                        acc[i][j] += av[i][kk] * bv[kk][j];
        }
        #pragma unroll
        for (int i = 0; i < 4; ++i) {
            int row = row0 + rg * 4 + i;
            if (row < M) {
                float4 o = {acc[i][0], acc[i][1], acc[i][2], acc[i][3]};
                *(float4*)&C[row * 40 + cg * 4] = o;
            }
        }
    }
}

// layer-1 aggregate + epilogue: h1 = relu(sum*rin + b1) * rout   (width 128)
__global__ void spmm1_kernel(const int* __restrict__ csc_off, const int* __restrict__ csc_src,
                             const int* __restrict__ out_cnt, const float* __restrict__ G,
                             const float* __restrict__ b1, float* __restrict__ H) {
    int v = blockIdx.x;
    int f = threadIdx.x;
    int beg = csc_off[v], end = csc_off[v + 1];
    float acc = 0.f;
    for (int e = beg; e < end; ++e) {
        int u = csc_src[e];
        acc += G[u * 128 + f];
    }
    float rin = 1.f / sqrtf(fmaxf((float)(end - beg), 1.f));
    float rout = 1.f / sqrtf(fmaxf((float)out_cnt[v], 1.f));
    float x = acc * rin + b1[f];
    H[v * 128 + f] = fmaxf(x, 0.f) * rout;
}

// layer-2 aggregate + epilogue: out = sum*rin + b2   (width 40)
__global__ void spmm2_kernel(const int* __restrict__ csc_off, const int* __restrict__ csc_src,
                             const float* __restrict__ G2, const float* __restrict__ b2,
                             float* __restrict__ out) {
    int v = blockIdx.x;
    int f = threadIdx.x;
    int beg = csc_off[v], end = csc_off[v + 1];
    if (f < N_CLASSES) {
        float acc = 0.f;
        for (int e = beg; e < end; ++e) acc += G2[csc_src[e] * N_CLASSES + f];
        float rin = 1.f / sqrtf(fmaxf((float)(end - beg), 1.f));
        out[v * N_CLASSES + f] = acc * rin + b2[f];
    }
}

extern "C" void kernel_launch(void* const* d_in, const int* in_sizes, int n_in,
                              void* d_out, int out_size, void* d_ws, size_t ws_size,
                              hipStream_t stream) {
    const int*   feats = (const int*)d_in[0];
    const int*   src   = (const int*)d_in[1];
    const int*   dst   = (const int*)d_in[2];
    const float* emb   = (const float*)d_in[3];
    const float* W1    = (const float*)d_in[4];
    const float* b1    = (const float*)d_in[5];
    const float* W2    = (const float*)d_in[6];
    const float* b2    = (const float*)d_in[7];
    float* out = (float*)d_out;

    char* w = (char*)d_ws;
    int*   out_cnt   = (int*)(w + 0);
    int*   in_cnt    = (int*)(w + 200192);
    int*   csc_off   = (int*)(w + 400384);
    int*   cursor    = (int*)(w + 600576);
    int*   csc_src   = (int*)(w + 800768);
    int*   partials  = (int*)(w + 4000768);
    int*   block_off = (int*)(w + 4001792);
    float* hA        = (float*)(w + 4096000);
    float* hB        = (float*)(w + 29696000);

    // 1) zero degree counters (covers out_cnt + in_cnt region)
    zero_ints<<<(100096 + 255) / 256, 256, 0, stream>>>((int*)w, 100096);
    // 2) degree histograms
    degree_kernel<<<(N_EDGES + 255) / 256, 256, 0, stream>>>(src, dst, out_cnt, in_cnt, N_EDGES);
    // 3) 3-phase exclusive scan -> csc_off / cursor
    part_sums<<<SCAN_BLOCKS, 256, 0, stream>>>(in_cnt, partials);
    scan_partials<<<1, 256, 0, stream>>>(partials, block_off, csc_off);
    apply_scan<<<SCAN_BLOCKS, 256, 0, stream>>>(in_cnt, block_off, csc_off, cursor);
    // 4) CSC fill (counting-sort placement)
    fill_csc<<<(N_EDGES + 255) / 256, 256, 0, stream>>>(src, dst, cursor, csc_src, N_EDGES);
    // 5) embedding mean-pool (+rsqrt(out_deg) fold) -> hA = h0_scaled
    pool_kernel<<<N_NODES, 128, 0, stream>>>(feats, emb, out_cnt, hA);
    // 6) G1 = h0_scaled @ W1 -> hB
    gemm1_kernel<<<dim3((N_NODES + 63) / 64, 2), 256, 0, stream>>>(hA, W1, hB, N_NODES);
    // 7) h1 = relu(agg(G1)*rin + b1)*rout -> hA
    spmm1_kernel<<<N_NODES, 128, 0, stream>>>(csc_off, csc_src, out_cnt, hB, b1, hA);
    // 8) G2 = h1 @ W2 -> hB
    gemm2_kernel<<<(N_NODES + 63) / 64, 256, 0, stream>>>(hA, W2, hB, N_NODES);
    // 9) out = agg(G2)*rin + b2
    spmm2_kernel<<<N_NODES, 64, 0, stream>>>(csc_off, csc_src, hB, b2, out);
}

// Round 3
// 429.833 us; speedup vs baseline: 1.3645x; 1.1316x over previous
//
#include <hip/hip_runtime.h>
#include <math.h>

#define N_NODES 50000
#define N_EDGES 800000
#define IN_FEATS 128
#define N_HIDDEN 128
#define N_CLASSES 40
#define SEQ_LEN 20
#define SCAN_BLOCKS 196   // ceil(50000/256)

__global__ void zero_ints(int* __restrict__ p, int n) {
    int i = blockIdx.x * blockDim.x + threadIdx.x;
    if (i < n) p[i] = 0;
}

__global__ void degree_kernel(const int* __restrict__ src, const int* __restrict__ dst,
                              int* __restrict__ out_cnt, int* __restrict__ in_cnt, int n_edges) {
    int e = blockIdx.x * blockDim.x + threadIdx.x;
    if (e < n_edges) {
        atomicAdd(&out_cnt[src[e]], 1);
        atomicAdd(&in_cnt[dst[e]], 1);
    }
}

// ---- 3-phase exclusive scan of in_cnt[50000] -> csc_off / cursor ----
__global__ __launch_bounds__(256) void part_sums(const int* __restrict__ in_cnt,
                                                 int* __restrict__ partials) {
    __shared__ int s[256];
    int t = threadIdx.x;
    int i = blockIdx.x * 256 + t;
    s[t] = (i < N_NODES) ? in_cnt[i] : 0;
    __syncthreads();
    #pragma unroll
    for (int d = 128; d > 0; d >>= 1) {
        if (t < d) s[t] += s[t + d];
        __syncthreads();
    }
    if (t == 0) partials[blockIdx.x] = s[0];
}

__global__ __launch_bounds__(256) void scan_partials(const int* __restrict__ partials,
                                                     int* __restrict__ block_off,
                                                     int* __restrict__ csc_off) {
    __shared__ int s[256];
    int t = threadIdx.x;
    int v = (t < SCAN_BLOCKS) ? partials[t] : 0;
    s[t] = v;
    __syncthreads();
    #pragma unroll
    for (int d = 1; d < 256; d <<= 1) {
        int x = (t >= d) ? s[t - d] : 0;
        __syncthreads();
        s[t] += x;
        __syncthreads();
    }
    block_off[t] = s[t] - v;                  // exclusive
    if (t == 255) csc_off[N_NODES] = s[255];  // grand total
}

__global__ __launch_bounds__(256) void apply_scan(const int* __restrict__ in_cnt,
                                                  const int* __restrict__ block_off,
                                                  int* __restrict__ csc_off,
                                                  int* __restrict__ cursor) {
    __shared__ int s[256];
    int t = threadIdx.x;
    int i = blockIdx.x * 256 + t;
    int v = (i < N_NODES) ? in_cnt[i] : 0;
    s[t] = v;
    __syncthreads();
    #pragma unroll
    for (int d = 1; d < 256; d <<= 1) {
        int x = (t >= d) ? s[t - d] : 0;
        __syncthreads();
        s[t] += x;
        __syncthreads();
    }
    if (i < N_NODES) {
        int o = block_off[blockIdx.x] + s[t] - v;
        csc_off[i] = o;
        cursor[i] = o;
    }
}

__global__ void fill_csc(const int* __restrict__ src, const int* __restrict__ dst,
                         int* __restrict__ cursor, int* __restrict__ csc_src, int n_edges) {
    int e = blockIdx.x * blockDim.x + threadIdx.x;
    if (e < n_edges) {
        int p = atomicAdd(&cursor[dst[e]], 1);
        csc_src[p] = src[e];
    }
}

// embedding mean-pool + fold in rsqrt(out_deg) scaling for layer-1 GEMM input
__global__ void pool_kernel(const int* __restrict__ feats, const float* __restrict__ emb,
                            const int* __restrict__ out_cnt, float* __restrict__ h0) {
    int v = blockIdx.x;
    int f = threadIdx.x;
    const int* tk = feats + v * SEQ_LEN;
    float acc = 0.f;
    int cnt = 0;
    #pragma unroll
    for (int t = 0; t < SEQ_LEN; ++t) {
        int tok = tk[t];
        cnt += (tok != 0);
        acc += emb[tok * IN_FEATS + f];       // pad row 0 is all-zero, safe to sum
    }
    float rout = 1.f / sqrtf(fmaxf((float)out_cnt[v], 1.f));
    float scale = rout / (float)max(cnt, 1);
    h0[v * IN_FEATS + f] = acc * scale;
}

// C[M,128] = A[M,128] @ W[128,128]; 64x64 tile, 256 threads, 4x4/thread
__global__ __launch_bounds__(256) void gemm1_kernel(const float* __restrict__ A,
                                                    const float* __restrict__ W,
                                                    float* __restrict__ C, int M) {
    __shared__ __align__(16) float As[64][132];
    __shared__ __align__(16) float Bs[128][64];
    const int t = threadIdx.x;
    const int row0 = blockIdx.x * 64;
    const int col0 = blockIdx.y * 64;
    #pragma unroll 8
    for (int i = 0; i < 32; ++i) {
        int idx = i * 256 + t;
        int r = idx >> 7, k = idx & 127;
        int row = row0 + r;
        As[r][k] = (row < M) ? A[row * 128 + k] : 0.f;
    }
    #pragma unroll 8
    for (int i = 0; i < 32; ++i) {
        int idx = i * 256 + t;
        int k = idx >> 6, c = idx & 63;
        Bs[k][c] = W[k * 128 + col0 + c];
    }
    __syncthreads();
    const int cg = t & 15, rg = t >> 4;
    float acc[4][4] = {};
    for (int k = 0; k < 128; k += 4) {
        float4 a0 = *(const float4*)&As[rg * 4 + 0][k];
        float4 a1 = *(const float4*)&As[rg * 4 + 1][k];
        float4 a2 = *(const float4*)&As[rg * 4 + 2][k];
        float4 a3 = *(const float4*)&As[rg * 4 + 3][k];
        float4 b0 = *(const float4*)&Bs[k + 0][cg * 4];
        float4 b1 = *(const float4*)&Bs[k + 1][cg * 4];
        float4 b2 = *(const float4*)&Bs[k + 2][cg * 4];
        float4 b3 = *(const float4*)&Bs[k + 3][cg * 4];
        float av[4][4] = {{a0.x, a0.y, a0.z, a0.w}, {a1.x, a1.y, a1.z, a1.w},
                          {a2.x, a2.y, a2.z, a2.w}, {a3.x, a3.y, a3.z, a3.w}};
        float bv[4][4] = {{b0.x, b0.y, b0.z, b0.w}, {b1.x, b1.y, b1.z, b1.w},
                          {b2.x, b2.y, b2.z, b2.w}, {b3.x, b3.y, b3.z, b3.w}};
        #pragma unroll
        for (int i = 0; i < 4; ++i)
            #pragma unroll
            for (int kk = 0; kk < 4; ++kk)
                #pragma unroll
                for (int j = 0; j < 4; ++j)
                    acc[i][j] += av[i][kk] * bv[kk][j];
    }
    #pragma unroll
    for (int i = 0; i < 4; ++i) {
        int row = row0 + rg * 4 + i;
        if (row < M) {
            float4 o = {acc[i][0], acc[i][1], acc[i][2], acc[i][3]};
            *(float4*)&C[row * 128 + col0 + cg * 4] = o;
        }
    }
}

// C[M,40] = A[M,128] @ W[128,40]; 64-row tile, 256 threads, cg<10 active
__global__ __launch_bounds__(256) void gemm2_kernel(const float* __restrict__ A,
                                                    const float* __restrict__ W,
                                                    float* __restrict__ C, int M) {
    __shared__ __align__(16) float As[64][132];
    __shared__ __align__(16) float Bs[128 * 40];
    const int t = threadIdx.x;
    const int row0 = blockIdx.x * 64;
    #pragma unroll 8
    for (int i = 0; i < 32; ++i) {
        int idx = i * 256 + t;
        int r = idx >> 7, k = idx & 127;
        int row = row0 + r;
        As[r][k] = (row < M) ? A[row * 128 + k] : 0.f;
    }
    for (int idx = t; idx < 128 * 40; idx += 256) Bs[idx] = W[idx];
    __syncthreads();
    const int cg = t & 15, rg = t >> 4;
    float acc[4][4] = {};
    if (cg < 10) {
        for (int k = 0; k < 128; k += 4) {
            float4 a0 = *(const float4*)&As[rg * 4 + 0][k];
            float4 a1 = *(const float4*)&As[rg * 4 + 1][k];
            float4 a2 = *(const float4*)&As[rg * 4 + 2][k];
            float4 a3 = *(const float4*)&As[rg * 4 + 3][k];
            float4 b0 = *(const float4*)&Bs[(k + 0) * 40 + cg * 4];
            float4 b1 = *(const float4*)&Bs[(k + 1) * 40 + cg * 4];
            float4 b2 = *(const float4*)&Bs[(k + 2) * 40 + cg * 4];
            float4 b3 = *(const float4*)&Bs[(k + 3) * 40 + cg * 4];
            float av[4][4] = {{a0.x, a0.y, a0.z, a0.w}, {a1.x, a1.y, a1.z, a1.w},
                              {a2.x, a2.y, a2.z, a2.w}, {a3.x, a3.y, a3.z, a3.w}};
            float bv[4][4] = {{b0.x, b0.y, b0.z, b0.w}, {b1.x, b1.y, b1.z, b1.w},
                              {b2.x, b2.y, b2.z, b2.w}, {b3.x, b3.y, b3.z, b3.w}};
            #pragma unroll
            for (int i = 0; i < 4; ++i)
                #pragma unroll
                for (int kk = 0; kk < 4; ++kk)
                    #pragma unroll
                    for (int j = 0; j < 4; ++j)
                        acc[i][j] += av[i][kk] * bv[kk][j];
        }
        #pragma unroll
        for (int i = 0; i < 4; ++i) {
            int row = row0 + rg * 4 + i;
            if (row < M) {
                float4 o = {acc[i][0], acc[i][1], acc[i][2], acc[i][3]};
                *(float4*)&C[row * 40 + cg * 4] = o;
            }
        }
    }
}

// layer-1 aggregate + epilogue: h1 = relu(sum*rin + b1) * rout   (width 128)
// 8 independent gathers in flight per wave to hide L2/L3 latency.
__global__ void spmm1_kernel(const int* __restrict__ csc_off, const int* __restrict__ csc_src,
                             const int* __restrict__ out_cnt, const float* __restrict__ G,
                             const float* __restrict__ b1, float* __restrict__ H) {
    int v = blockIdx.x;
    int f = threadIdx.x;
    int beg = csc_off[v], end = csc_off[v + 1];
    float acc = 0.f;
    int e = beg;
    for (; e + 8 <= end; e += 8) {
        int u0 = csc_src[e + 0], u1 = csc_src[e + 1], u2 = csc_src[e + 2], u3 = csc_src[e + 3];
        int u4 = csc_src[e + 4], u5 = csc_src[e + 5], u6 = csc_src[e + 6], u7 = csc_src[e + 7];
        float g0 = G[u0 * 128 + f];
        float g1 = G[u1 * 128 + f];
        float g2 = G[u2 * 128 + f];
        float g3 = G[u3 * 128 + f];
        float g4 = G[u4 * 128 + f];
        float g5 = G[u5 * 128 + f];
        float g6 = G[u6 * 128 + f];
        float g7 = G[u7 * 128 + f];
        acc += ((g0 + g1) + (g2 + g3)) + ((g4 + g5) + (g6 + g7));
    }
    if (e + 4 <= end) {
        int u0 = csc_src[e + 0], u1 = csc_src[e + 1], u2 = csc_src[e + 2], u3 = csc_src[e + 3];
        float g0 = G[u0 * 128 + f];
        float g1 = G[u1 * 128 + f];
        float g2 = G[u2 * 128 + f];
        float g3 = G[u3 * 128 + f];
        acc += (g0 + g1) + (g2 + g3);
        e += 4;
    }
    for (; e < end; ++e) acc += G[csc_src[e] * 128 + f];
    float rin = 1.f / sqrtf(fmaxf((float)(end - beg), 1.f));
    float rout = 1.f / sqrtf(fmaxf((float)out_cnt[v], 1.f));
    float x = acc * rin + b1[f];
    H[v * 128 + f] = fmaxf(x, 0.f) * rout;
}

// layer-2 aggregate + epilogue: out = sum*rin + b2   (width 40)
__global__ void spmm2_kernel(const int* __restrict__ csc_off, const int* __restrict__ csc_src,
                             const float* __restrict__ G2, const float* __restrict__ b2,
                             float* __restrict__ out) {
    int v = blockIdx.x;
    int f = threadIdx.x;
    int beg = csc_off[v], end = csc_off[v + 1];
    if (f < N_CLASSES) {
        float acc = 0.f;
        int e = beg;
        for (; e + 8 <= end; e += 8) {
            int u0 = csc_src[e + 0], u1 = csc_src[e + 1], u2 = csc_src[e + 2], u3 = csc_src[e + 3];
            int u4 = csc_src[e + 4], u5 = csc_src[e + 5], u6 = csc_src[e + 6], u7 = csc_src[e + 7];
            float g0 = G2[u0 * N_CLASSES + f];
            float g1 = G2[u1 * N_CLASSES + f];
            float g2 = G2[u2 * N_CLASSES + f];
            float g3 = G2[u3 * N_CLASSES + f];
            float g4 = G2[u4 * N_CLASSES + f];
            float g5 = G2[u5 * N_CLASSES + f];
            float g6 = G2[u6 * N_CLASSES + f];
            float g7 = G2[u7 * N_CLASSES + f];
            acc += ((g0 + g1) + (g2 + g3)) + ((g4 + g5) + (g6 + g7));
        }
        if (e + 4 <= end) {
            int u0 = csc_src[e + 0], u1 = csc_src[e + 1], u2 = csc_src[e + 2], u3 = csc_src[e + 3];
            float g0 = G2[u0 * N_CLASSES + f];
            float g1 = G2[u1 * N_CLASSES + f];
            float g2 = G2[u2 * N_CLASSES + f];
            float g3 = G2[u3 * N_CLASSES + f];
            acc += (g0 + g1) + (g2 + g3);
            e += 4;
        }
        for (; e < end; ++e) acc += G2[csc_src[e] * N_CLASSES + f];
        float rin = 1.f / sqrtf(fmaxf((float)(end - beg), 1.f));
        out[v * N_CLASSES + f] = acc * rin + b2[f];
    }
}

extern "C" void kernel_launch(void* const* d_in, const int* in_sizes, int n_in,
                              void* d_out, int out_size, void* d_ws, size_t ws_size,
                              hipStream_t stream) {
    const int*   feats = (const int*)d_in[0];
    const int*   src   = (const int*)d_in[1];
    const int*   dst   = (const int*)d_in[2];
    const float* emb   = (const float*)d_in[3];
    const float* W1    = (const float*)d_in[4];
    const float* b1    = (const float*)d_in[5];
    const float* W2    = (const float*)d_in[6];
    const float* b2    = (const float*)d_in[7];
    float* out = (float*)d_out;

    char* w = (char*)d_ws;
    int*   out_cnt   = (int*)(w + 0);
    int*   in_cnt    = (int*)(w + 200192);
    int*   csc_off   = (int*)(w + 400384);
    int*   cursor    = (int*)(w + 600576);
    int*   csc_src   = (int*)(w + 800768);
    int*   partials  = (int*)(w + 4000768);
    int*   block_off = (int*)(w + 4001792);
    float* hA        = (float*)(w + 4096000);
    float* hB        = (float*)(w + 29696000);

    zero_ints<<<(100096 + 255) / 256, 256, 0, stream>>>((int*)w, 100096);
    degree_kernel<<<(N_EDGES + 255) / 256, 256, 0, stream>>>(src, dst, out_cnt, in_cnt, N_EDGES);
    part_sums<<<SCAN_BLOCKS, 256, 0, stream>>>(in_cnt, partials);
    scan_partials<<<1, 256, 0, stream>>>(partials, block_off, csc_off);
    apply_scan<<<SCAN_BLOCKS, 256, 0, stream>>>(in_cnt, block_off, csc_off, cursor);
    fill_csc<<<(N_EDGES + 255) / 256, 256, 0, stream>>>(src, dst, cursor, csc_src, N_EDGES);
    pool_kernel<<<N_NODES, 128, 0, stream>>>(feats, emb, out_cnt, hA);
    gemm1_kernel<<<dim3((N_NODES + 63) / 64, 2), 256, 0, stream>>>(hA, W1, hB, N_NODES);
    spmm1_kernel<<<N_NODES, 128, 0, stream>>>(csc_off, csc_src, out_cnt, hB, b1, hA);
    gemm2_kernel<<<(N_NODES + 63) / 64, 256, 0, stream>>>(hA, W2, hB, N_NODES);
    spmm2_kernel<<<N_NODES, 64, 0, stream>>>(csc_off, csc_src, hB, b2, out);
}

// Round 4
// 427.556 us; speedup vs baseline: 1.3718x; 1.0053x over previous
//
#include <hip/hip_runtime.h>
#include <math.h>

#define N_NODES 50000
#define N_EDGES 800000
#define IN_FEATS 128
#define N_HIDDEN 128
#define N_CLASSES 40
#define SEQ_LEN 20
#define SCAN_BLOCKS 196   // ceil(50000/256)
#define NREP 8

// ---------------- workspace layout (bytes) ----------------
// Overlay plan: rep arrays / cursors / partials are dead before pool_kernel
// writes hA, so hA overlays them.
//   in_rep  : 0          int[8*50000]   (1.6 MB)   \ zeroed each call
//   out_rep : 1600000    int[8*50000]   (1.6 MB)   /
//   cursor  : 3200000    int[8*50000]   (1.6 MB)
//   partials: 4800000    int[256]
//   block_off:4802048    int[256]
//   hA      : 0          float[50000*128] (25.6 MB, overlays all of the above)
//   csc_off : 25600000   int[50001]
//   out_cnt : 25800448   int[50000]
//   csc_src : 26000448   int[800000]   (3.2 MB)
//   hB      : 29200448   float[50000*128] (25.6 MB)  -> total ~54.8 MB

__global__ void zero_int4(int4* __restrict__ p, int n4) {
    int i = blockIdx.x * blockDim.x + threadIdx.x;
    if (i < n4) p[i] = make_int4(0, 0, 0, 0);
}

// 2 edges/thread; replica = blockIdx & 7 (must match fill_csc's mapping)
__global__ void degree_kernel(const int* __restrict__ src, const int* __restrict__ dst,
                              int* __restrict__ out_rep, int* __restrict__ in_rep, int n_edges) {
    int gid = blockIdx.x * blockDim.x + threadIdx.x;
    int r = blockIdx.x & (NREP - 1);
    int* orp = out_rep + r * N_NODES;
    int* irp = in_rep + r * N_NODES;
    int e = gid * 2;
    if (e < n_edges) {
        atomicAdd(&orp[src[e]], 1);
        atomicAdd(&irp[dst[e]], 1);
    }
    if (e + 1 < n_edges) {
        atomicAdd(&orp[src[e + 1]], 1);
        atomicAdd(&irp[dst[e + 1]], 1);
    }
}

// ---- 3-phase exclusive scan over summed in-replicas ----
__global__ __launch_bounds__(256) void part_sums(const int* __restrict__ in_rep,
                                                 int* __restrict__ partials) {
    __shared__ int s[256];
    int t = threadIdx.x;
    int i = blockIdx.x * 256 + t;
    int v = 0;
    if (i < N_NODES) {
        #pragma unroll
        for (int r = 0; r < NREP; ++r) v += in_rep[r * N_NODES + i];
    }
    s[t] = v;
    __syncthreads();
    #pragma unroll
    for (int d = 128; d > 0; d >>= 1) {
        if (t < d) s[t] += s[t + d];
        __syncthreads();
    }
    if (t == 0) partials[blockIdx.x] = s[0];
}

__global__ __launch_bounds__(256) void scan_partials(const int* __restrict__ partials,
                                                     int* __restrict__ block_off,
                                                     int* __restrict__ csc_off) {
    __shared__ int s[256];
    int t = threadIdx.x;
    int v = (t < SCAN_BLOCKS) ? partials[t] : 0;
    s[t] = v;
    __syncthreads();
    #pragma unroll
    for (int d = 1; d < 256; d <<= 1) {
        int x = (t >= d) ? s[t - d] : 0;
        __syncthreads();
        s[t] += x;
        __syncthreads();
    }
    block_off[t] = s[t] - v;                  // exclusive
    if (t == 255) csc_off[N_NODES] = s[255];  // grand total
}

// block-local scan + per-replica cursor bases + out_cnt reduction
__global__ __launch_bounds__(256) void apply_scan(const int* __restrict__ in_rep,
                                                  const int* __restrict__ out_rep,
                                                  const int* __restrict__ block_off,
                                                  int* __restrict__ csc_off,
                                                  int* __restrict__ cursor,
                                                  int* __restrict__ out_cnt) {
    __shared__ int s[256];
    int t = threadIdx.x;
    int i = blockIdx.x * 256 + t;
    int rv[NREP];
    int v = 0;
    if (i < N_NODES) {
        #pragma unroll
        for (int r = 0; r < NREP; ++r) { rv[r] = in_rep[r * N_NODES + i]; v += rv[r]; }
    } else {
        #pragma unroll
        for (int r = 0; r < NREP; ++r) rv[r] = 0;
    }
    s[t] = v;
    __syncthreads();
    #pragma unroll
    for (int d = 1; d < 256; d <<= 1) {
        int x = (t >= d) ? s[t - d] : 0;
        __syncthreads();
        s[t] += x;
        __syncthreads();
    }
    if (i < N_NODES) {
        int o = block_off[blockIdx.x] + s[t] - v;
        csc_off[i] = o;
        int run = o;
        #pragma unroll
        for (int r = 0; r < NREP; ++r) { cursor[r * N_NODES + i] = run; run += rv[r]; }
        int oc = 0;
        #pragma unroll
        for (int r = 0; r < NREP; ++r) oc += out_rep[r * N_NODES + i];
        out_cnt[i] = oc;
    }
}

// 2 edges/thread; replica mapping identical to degree_kernel
__global__ void fill_csc(const int* __restrict__ src, const int* __restrict__ dst,
                         int* __restrict__ cursor, int* __restrict__ csc_src, int n_edges) {
    int gid = blockIdx.x * blockDim.x + threadIdx.x;
    int r = blockIdx.x & (NREP - 1);
    int* cur = cursor + r * N_NODES;
    int e = gid * 2;
    if (e < n_edges) {
        int p = atomicAdd(&cur[dst[e]], 1);
        csc_src[p] = src[e];
    }
    if (e + 1 < n_edges) {
        int p = atomicAdd(&cur[dst[e + 1]], 1);
        csc_src[p] = src[e + 1];
    }
}

// embedding mean-pool + fold in rsqrt(out_deg) scaling for layer-1 GEMM input
__global__ void pool_kernel(const int* __restrict__ feats, const float* __restrict__ emb,
                            const int* __restrict__ out_cnt, float* __restrict__ h0) {
    int v = blockIdx.x;
    int f = threadIdx.x;
    const int* tk = feats + v * SEQ_LEN;
    float acc = 0.f;
    int cnt = 0;
    #pragma unroll
    for (int t = 0; t < SEQ_LEN; ++t) {
        int tok = tk[t];
        cnt += (tok != 0);
        acc += emb[tok * IN_FEATS + f];       // pad row 0 is all-zero, safe to sum
    }
    float rout = 1.f / sqrtf(fmaxf((float)out_cnt[v], 1.f));
    float scale = rout / (float)max(cnt, 1);
    h0[v * IN_FEATS + f] = acc * scale;
}

// C[M,128] = A[M,128] @ W[128,128]; 64x64 tile, 256 threads, 4x4/thread
__global__ __launch_bounds__(256) void gemm1_kernel(const float* __restrict__ A,
                                                    const float* __restrict__ W,
                                                    float* __restrict__ C, int M) {
    __shared__ __align__(16) float As[64][132];
    __shared__ __align__(16) float Bs[128][64];
    const int t = threadIdx.x;
    const int row0 = blockIdx.x * 64;
    const int col0 = blockIdx.y * 64;
    #pragma unroll 8
    for (int i = 0; i < 32; ++i) {
        int idx = i * 256 + t;
        int r = idx >> 7, k = idx & 127;
        int row = row0 + r;
        As[r][k] = (row < M) ? A[row * 128 + k] : 0.f;
    }
    #pragma unroll 8
    for (int i = 0; i < 32; ++i) {
        int idx = i * 256 + t;
        int k = idx >> 6, c = idx & 63;
        Bs[k][c] = W[k * 128 + col0 + c];
    }
    __syncthreads();
    const int cg = t & 15, rg = t >> 4;
    float acc[4][4] = {};
    for (int k = 0; k < 128; k += 4) {
        float4 a0 = *(const float4*)&As[rg * 4 + 0][k];
        float4 a1 = *(const float4*)&As[rg * 4 + 1][k];
        float4 a2 = *(const float4*)&As[rg * 4 + 2][k];
        float4 a3 = *(const float4*)&As[rg * 4 + 3][k];
        float4 b0 = *(const float4*)&Bs[k + 0][cg * 4];
        float4 b1 = *(const float4*)&Bs[k + 1][cg * 4];
        float4 b2 = *(const float4*)&Bs[k + 2][cg * 4];
        float4 b3 = *(const float4*)&Bs[k + 3][cg * 4];
        float av[4][4] = {{a0.x, a0.y, a0.z, a0.w}, {a1.x, a1.y, a1.z, a1.w},
                          {a2.x, a2.y, a2.z, a2.w}, {a3.x, a3.y, a3.z, a3.w}};
        float bv[4][4] = {{b0.x, b0.y, b0.z, b0.w}, {b1.x, b1.y, b1.z, b1.w},
                          {b2.x, b2.y, b2.z, b2.w}, {b3.x, b3.y, b3.z, b3.w}};
        #pragma unroll
        for (int i = 0; i < 4; ++i)
            #pragma unroll
            for (int kk = 0; kk < 4; ++kk)
                #pragma unroll
                for (int j = 0; j < 4; ++j)
                    acc[i][j] += av[i][kk] * bv[kk][j];
    }
    #pragma unroll
    for (int i = 0; i < 4; ++i) {
        int row = row0 + rg * 4 + i;
        if (row < M) {
            float4 o = {acc[i][0], acc[i][1], acc[i][2], acc[i][3]};
            *(float4*)&C[row * 128 + col0 + cg * 4] = o;
        }
    }
}

// C[M,40] = A[M,128] @ W[128,40]; 64-row tile, 256 threads, cg<10 active
__global__ __launch_bounds__(256) void gemm2_kernel(const float* __restrict__ A,
                                                    const float* __restrict__ W,
                                                    float* __restrict__ C, int M) {
    __shared__ __align__(16) float As[64][132];
    __shared__ __align__(16) float Bs[128 * 40];
    const int t = threadIdx.x;
    const int row0 = blockIdx.x * 64;
    #pragma unroll 8
    for (int i = 0; i < 32; ++i) {
        int idx = i * 256 + t;
        int r = idx >> 7, k = idx & 127;
        int row = row0 + r;
        As[r][k] = (row < M) ? A[row * 128 + k] : 0.f;
    }
    for (int idx = t; idx < 128 * 40; idx += 256) Bs[idx] = W[idx];
    __syncthreads();
    const int cg = t & 15, rg = t >> 4;
    float acc[4][4] = {};
    if (cg < 10) {
        for (int k = 0; k < 128; k += 4) {
            float4 a0 = *(const float4*)&As[rg * 4 + 0][k];
            float4 a1 = *(const float4*)&As[rg * 4 + 1][k];
            float4 a2 = *(const float4*)&As[rg * 4 + 2][k];
            float4 a3 = *(const float4*)&As[rg * 4 + 3][k];
            float4 b0 = *(const float4*)&Bs[(k + 0) * 40 + cg * 4];
            float4 b1 = *(const float4*)&Bs[(k + 1) * 40 + cg * 4];
            float4 b2 = *(const float4*)&Bs[(k + 2) * 40 + cg * 4];
            float4 b3 = *(const float4*)&Bs[(k + 3) * 40 + cg * 4];
            float av[4][4] = {{a0.x, a0.y, a0.z, a0.w}, {a1.x, a1.y, a1.z, a1.w},
                              {a2.x, a2.y, a2.z, a2.w}, {a3.x, a3.y, a3.z, a3.w}};
            float bv[4][4] = {{b0.x, b0.y, b0.z, b0.w}, {b1.x, b1.y, b1.z, b1.w},
                              {b2.x, b2.y, b2.z, b2.w}, {b3.x, b3.y, b3.z, b3.w}};
            #pragma unroll
            for (int i = 0; i < 4; ++i)
                #pragma unroll
                for (int kk = 0; kk < 4; ++kk)
                    #pragma unroll
                    for (int j = 0; j < 4; ++j)
                        acc[i][j] += av[i][kk] * bv[kk][j];
        }
        #pragma unroll
        for (int i = 0; i < 4; ++i) {
            int row = row0 + rg * 4 + i;
            if (row < M) {
                float4 o = {acc[i][0], acc[i][1], acc[i][2], acc[i][3]};
                *(float4*)&C[row * 40 + cg * 4] = o;
            }
        }
    }
}

// layer-1 aggregate + epilogue: h1 = relu(sum*rin + b1) * rout   (width 128)
__global__ void spmm1_kernel(const int* __restrict__ csc_off, const int* __restrict__ csc_src,
                             const int* __restrict__ out_cnt, const float* __restrict__ G,
                             const float* __restrict__ b1, float* __restrict__ H) {
    int v = blockIdx.x;
    int f = threadIdx.x;
    int beg = csc_off[v], end = csc_off[v + 1];
    float acc = 0.f;
    int e = beg;
    for (; e + 8 <= end; e += 8) {
        int u0 = csc_src[e + 0], u1 = csc_src[e + 1], u2 = csc_src[e + 2], u3 = csc_src[e + 3];
        int u4 = csc_src[e + 4], u5 = csc_src[e + 5], u6 = csc_src[e + 6], u7 = csc_src[e + 7];
        float g0 = G[u0 * 128 + f];
        float g1 = G[u1 * 128 + f];
        float g2 = G[u2 * 128 + f];
        float g3 = G[u3 * 128 + f];
        float g4 = G[u4 * 128 + f];
        float g5 = G[u5 * 128 + f];
        float g6 = G[u6 * 128 + f];
        float g7 = G[u7 * 128 + f];
        acc += ((g0 + g1) + (g2 + g3)) + ((g4 + g5) + (g6 + g7));
    }
    if (e + 4 <= end) {
        int u0 = csc_src[e + 0], u1 = csc_src[e + 1], u2 = csc_src[e + 2], u3 = csc_src[e + 3];
        float g0 = G[u0 * 128 + f];
        float g1 = G[u1 * 128 + f];
        float g2 = G[u2 * 128 + f];
        float g3 = G[u3 * 128 + f];
        acc += (g0 + g1) + (g2 + g3);
        e += 4;
    }
    for (; e < end; ++e) acc += G[csc_src[e] * 128 + f];
    float rin = 1.f / sqrtf(fmaxf((float)(end - beg), 1.f));
    float rout = 1.f / sqrtf(fmaxf((float)out_cnt[v], 1.f));
    float x = acc * rin + b1[f];
    H[v * 128 + f] = fmaxf(x, 0.f) * rout;
}

// layer-2 aggregate + epilogue: out = sum*rin + b2   (width 40)
__global__ void spmm2_kernel(const int* __restrict__ csc_off, const int* __restrict__ csc_src,
                             const float* __restrict__ G2, const float* __restrict__ b2,
                             float* __restrict__ out) {
    int v = blockIdx.x;
    int f = threadIdx.x;
    int beg = csc_off[v], end = csc_off[v + 1];
    if (f < N_CLASSES) {
        float acc = 0.f;
        int e = beg;
        for (; e + 8 <= end; e += 8) {
            int u0 = csc_src[e + 0], u1 = csc_src[e + 1], u2 = csc_src[e + 2], u3 = csc_src[e + 3];
            int u4 = csc_src[e + 4], u5 = csc_src[e + 5], u6 = csc_src[e + 6], u7 = csc_src[e + 7];
            float g0 = G2[u0 * N_CLASSES + f];
            float g1 = G2[u1 * N_CLASSES + f];
            float g2 = G2[u2 * N_CLASSES + f];
            float g3 = G2[u3 * N_CLASSES + f];
            float g4 = G2[u4 * N_CLASSES + f];
            float g5 = G2[u5 * N_CLASSES + f];
            float g6 = G2[u6 * N_CLASSES + f];
            float g7 = G2[u7 * N_CLASSES + f];
            acc += ((g0 + g1) + (g2 + g3)) + ((g4 + g5) + (g6 + g7));
        }
        if (e + 4 <= end) {
            int u0 = csc_src[e + 0], u1 = csc_src[e + 1], u2 = csc_src[e + 2], u3 = csc_src[e + 3];
            float g0 = G2[u0 * N_CLASSES + f];
            float g1 = G2[u1 * N_CLASSES + f];
            float g2 = G2[u2 * N_CLASSES + f];
            float g3 = G2[u3 * N_CLASSES + f];
            acc += (g0 + g1) + (g2 + g3);
            e += 4;
        }
        for (; e < end; ++e) acc += G2[csc_src[e] * N_CLASSES + f];
        float rin = 1.f / sqrtf(fmaxf((float)(end - beg), 1.f));
        out[v * N_CLASSES + f] = acc * rin + b2[f];
    }
}

extern "C" void kernel_launch(void* const* d_in, const int* in_sizes, int n_in,
                              void* d_out, int out_size, void* d_ws, size_t ws_size,
                              hipStream_t stream) {
    const int*   feats = (const int*)d_in[0];
    const int*   src   = (const int*)d_in[1];
    const int*   dst   = (const int*)d_in[2];
    const float* emb   = (const float*)d_in[3];
    const float* W1    = (const float*)d_in[4];
    const float* b1    = (const float*)d_in[5];
    const float* W2    = (const float*)d_in[6];
    const float* b2    = (const float*)d_in[7];
    float* out = (float*)d_out;

    char* w = (char*)d_ws;
    int*   in_rep    = (int*)(w + 0);         // dead after apply_scan
    int*   out_rep   = (int*)(w + 1600000);   // dead after apply_scan
    int*   cursor    = (int*)(w + 3200000);   // dead after fill_csc
    int*   partials  = (int*)(w + 4800000);   // dead after scan_partials
    int*   block_off = (int*)(w + 4802048);   // dead after apply_scan
    float* hA        = (float*)(w + 0);       // overlays the above (written by pool)
    int*   csc_off   = (int*)(w + 25600000);
    int*   out_cnt   = (int*)(w + 25800448);
    int*   csc_src   = (int*)(w + 26000448);
    float* hB        = (float*)(w + 29200448);

    // 1) zero replica counters: 2*8*50000 ints = 200000 int4
    zero_int4<<<(200000 + 255) / 256, 256, 0, stream>>>((int4*)w, 200000);
    // 2) replicated degree histograms (2 edges/thread)
    degree_kernel<<<(N_EDGES / 2 + 255) / 256, 256, 0, stream>>>(src, dst, out_rep, in_rep, N_EDGES);
    // 3) 3-phase exclusive scan -> csc_off / per-replica cursors / out_cnt
    part_sums<<<SCAN_BLOCKS, 256, 0, stream>>>(in_rep, partials);
    scan_partials<<<1, 256, 0, stream>>>(partials, block_off, csc_off);
    apply_scan<<<SCAN_BLOCKS, 256, 0, stream>>>(in_rep, out_rep, block_off, csc_off, cursor, out_cnt);
    // 4) CSC fill, replica-partitioned cursors (mapping matches degree_kernel)
    fill_csc<<<(N_EDGES / 2 + 255) / 256, 256, 0, stream>>>(src, dst, cursor, csc_src, N_EDGES);
    // 5) embedding mean-pool (+rsqrt(out_deg) fold) -> hA
    pool_kernel<<<N_NODES, 128, 0, stream>>>(feats, emb, out_cnt, hA);
    // 6) G1 = h0_scaled @ W1 -> hB
    gemm1_kernel<<<dim3((N_NODES + 63) / 64, 2), 256, 0, stream>>>(hA, W1, hB, N_NODES);
    // 7) h1 = relu(agg(G1)*rin + b1)*rout -> hA
    spmm1_kernel<<<N_NODES, 128, 0, stream>>>(csc_off, csc_src, out_cnt, hB, b1, hA);
    // 8) G2 = h1 @ W2 -> hB
    gemm2_kernel<<<(N_NODES + 63) / 64, 256, 0, stream>>>(hA, W2, hB, N_NODES);
    // 9) out = agg(G2)*rin + b2
    spmm2_kernel<<<N_NODES, 64, 0, stream>>>(csc_off, csc_src, hB, b2, out);
}

// Round 5
// 406.197 us; speedup vs baseline: 1.4439x; 1.0526x over previous
//
#include <hip/hip_runtime.h>
#include <math.h>

#define N_NODES 50000
#define N_EDGES 800000
#define IN_FEATS 128
#define N_HIDDEN 128
#define N_CLASSES 40
#define SEQ_LEN 20
#define SCAN_BLOCKS 196   // ceil(50000/256)
#define NREP 8

// bf16 helpers (RNE)
__device__ inline unsigned short f2bf(float x) {
    union { float f; unsigned int u; } v; v.f = x;
    unsigned int r = v.u + 0x7FFF + ((v.u >> 16) & 1);
    return (unsigned short)(r >> 16);
}
__device__ inline float bf2f(unsigned short b) {
    union { float f; unsigned int u; } v; v.u = ((unsigned int)b) << 16;
    return v.f;
}

// ---------------- workspace layout (bytes) ----------------
//   in_rep  : 0          int[8*50000]   \ dead after apply_scan
//   out_rep : 1600000    int[8*50000]   /
//   cursor  : 3200000    int[8*50000]     dead after fill_csc
//   partials: 4800000    int[256]
//   block_off:4802048    int[256]
//   hA      : 0          float[50000*128] (25.6 MB, overlays the above)
//   csc_off : 25600000   int[50001]
//   out_cnt : 25800448   int[50000]
//   csc_src : 26000448   int[800000]
//   hB(bf16): 29200448   ushort[50000*128] (12.8 MB; G1 then G2)

__global__ void zero_int4(int4* __restrict__ p, int n4) {
    int i = blockIdx.x * blockDim.x + threadIdx.x;
    if (i < n4) p[i] = make_int4(0, 0, 0, 0);
}

__global__ void degree_kernel(const int* __restrict__ src, const int* __restrict__ dst,
                              int* __restrict__ out_rep, int* __restrict__ in_rep, int n_edges) {
    int gid = blockIdx.x * blockDim.x + threadIdx.x;
    int r = blockIdx.x & (NREP - 1);
    int* orp = out_rep + r * N_NODES;
    int* irp = in_rep + r * N_NODES;
    int e = gid * 2;
    if (e < n_edges) {
        atomicAdd(&orp[src[e]], 1);
        atomicAdd(&irp[dst[e]], 1);
    }
    if (e + 1 < n_edges) {
        atomicAdd(&orp[src[e + 1]], 1);
        atomicAdd(&irp[dst[e + 1]], 1);
    }
}

__global__ __launch_bounds__(256) void part_sums(const int* __restrict__ in_rep,
                                                 int* __restrict__ partials) {
    __shared__ int s[256];
    int t = threadIdx.x;
    int i = blockIdx.x * 256 + t;
    int v = 0;
    if (i < N_NODES) {
        #pragma unroll
        for (int r = 0; r < NREP; ++r) v += in_rep[r * N_NODES + i];
    }
    s[t] = v;
    __syncthreads();
    #pragma unroll
    for (int d = 128; d > 0; d >>= 1) {
        if (t < d) s[t] += s[t + d];
        __syncthreads();
    }
    if (t == 0) partials[blockIdx.x] = s[0];
}

__global__ __launch_bounds__(256) void scan_partials(const int* __restrict__ partials,
                                                     int* __restrict__ block_off,
                                                     int* __restrict__ csc_off) {
    __shared__ int s[256];
    int t = threadIdx.x;
    int v = (t < SCAN_BLOCKS) ? partials[t] : 0;
    s[t] = v;
    __syncthreads();
    #pragma unroll
    for (int d = 1; d < 256; d <<= 1) {
        int x = (t >= d) ? s[t - d] : 0;
        __syncthreads();
        s[t] += x;
        __syncthreads();
    }
    block_off[t] = s[t] - v;
    if (t == 255) csc_off[N_NODES] = s[255];
}

__global__ __launch_bounds__(256) void apply_scan(const int* __restrict__ in_rep,
                                                  const int* __restrict__ out_rep,
                                                  const int* __restrict__ block_off,
                                                  int* __restrict__ csc_off,
                                                  int* __restrict__ cursor,
                                                  int* __restrict__ out_cnt) {
    __shared__ int s[256];
    int t = threadIdx.x;
    int i = blockIdx.x * 256 + t;
    int rv[NREP];
    int v = 0;
    if (i < N_NODES) {
        #pragma unroll
        for (int r = 0; r < NREP; ++r) { rv[r] = in_rep[r * N_NODES + i]; v += rv[r]; }
    } else {
        #pragma unroll
        for (int r = 0; r < NREP; ++r) rv[r] = 0;
    }
    s[t] = v;
    __syncthreads();
    #pragma unroll
    for (int d = 1; d < 256; d <<= 1) {
        int x = (t >= d) ? s[t - d] : 0;
        __syncthreads();
        s[t] += x;
        __syncthreads();
    }
    if (i < N_NODES) {
        int o = block_off[blockIdx.x] + s[t] - v;
        csc_off[i] = o;
        int run = o;
        #pragma unroll
        for (int r = 0; r < NREP; ++r) { cursor[r * N_NODES + i] = run; run += rv[r]; }
        int oc = 0;
        #pragma unroll
        for (int r = 0; r < NREP; ++r) oc += out_rep[r * N_NODES + i];
        out_cnt[i] = oc;
    }
}

__global__ void fill_csc(const int* __restrict__ src, const int* __restrict__ dst,
                         int* __restrict__ cursor, int* __restrict__ csc_src, int n_edges) {
    int gid = blockIdx.x * blockDim.x + threadIdx.x;
    int r = blockIdx.x & (NREP - 1);
    int* cur = cursor + r * N_NODES;
    int e = gid * 2;
    if (e < n_edges) {
        int p = atomicAdd(&cur[dst[e]], 1);
        csc_src[p] = src[e];
    }
    if (e + 1 < n_edges) {
        int p = atomicAdd(&cur[dst[e + 1]], 1);
        csc_src[p] = src[e + 1];
    }
}

__global__ void pool_kernel(const int* __restrict__ feats, const float* __restrict__ emb,
                            const int* __restrict__ out_cnt, float* __restrict__ h0) {
    int v = blockIdx.x;
    int f = threadIdx.x;
    const int* tk = feats + v * SEQ_LEN;
    float acc = 0.f;
    int cnt = 0;
    #pragma unroll
    for (int t = 0; t < SEQ_LEN; ++t) {
        int tok = tk[t];
        cnt += (tok != 0);
        acc += emb[tok * IN_FEATS + f];
    }
    float rout = 1.f / sqrtf(fmaxf((float)out_cnt[v], 1.f));
    float scale = rout / (float)max(cnt, 1);
    h0[v * IN_FEATS + f] = acc * scale;
}

// C_bf16[M,128] = A[M,128] @ W[128,128]
__global__ __launch_bounds__(256) void gemm1_kernel(const float* __restrict__ A,
                                                    const float* __restrict__ W,
                                                    unsigned short* __restrict__ C, int M) {
    __shared__ __align__(16) float As[64][132];
    __shared__ __align__(16) float Bs[128][64];
    const int t = threadIdx.x;
    const int row0 = blockIdx.x * 64;
    const int col0 = blockIdx.y * 64;
    #pragma unroll 8
    for (int i = 0; i < 32; ++i) {
        int idx = i * 256 + t;
        int r = idx >> 7, k = idx & 127;
        int row = row0 + r;
        As[r][k] = (row < M) ? A[row * 128 + k] : 0.f;
    }
    #pragma unroll 8
    for (int i = 0; i < 32; ++i) {
        int idx = i * 256 + t;
        int k = idx >> 6, c = idx & 63;
        Bs[k][c] = W[k * 128 + col0 + c];
    }
    __syncthreads();
    const int cg = t & 15, rg = t >> 4;
    float acc[4][4] = {};
    for (int k = 0; k < 128; k += 4) {
        float4 a0 = *(const float4*)&As[rg * 4 + 0][k];
        float4 a1 = *(const float4*)&As[rg * 4 + 1][k];
        float4 a2 = *(const float4*)&As[rg * 4 + 2][k];
        float4 a3 = *(const float4*)&As[rg * 4 + 3][k];
        float4 b0 = *(const float4*)&Bs[k + 0][cg * 4];
        float4 b1 = *(const float4*)&Bs[k + 1][cg * 4];
        float4 b2 = *(const float4*)&Bs[k + 2][cg * 4];
        float4 b3 = *(const float4*)&Bs[k + 3][cg * 4];
        float av[4][4] = {{a0.x, a0.y, a0.z, a0.w}, {a1.x, a1.y, a1.z, a1.w},
                          {a2.x, a2.y, a2.z, a2.w}, {a3.x, a3.y, a3.z, a3.w}};
        float bv[4][4] = {{b0.x, b0.y, b0.z, b0.w}, {b1.x, b1.y, b1.z, b1.w},
                          {b2.x, b2.y, b2.z, b2.w}, {b3.x, b3.y, b3.z, b3.w}};
        #pragma unroll
        for (int i = 0; i < 4; ++i)
            #pragma unroll
            for (int kk = 0; kk < 4; ++kk)
                #pragma unroll
                for (int j = 0; j < 4; ++j)
                    acc[i][j] += av[i][kk] * bv[kk][j];
    }
    #pragma unroll
    for (int i = 0; i < 4; ++i) {
        int row = row0 + rg * 4 + i;
        if (row < M) {
            ushort4 o = {f2bf(acc[i][0]), f2bf(acc[i][1]), f2bf(acc[i][2]), f2bf(acc[i][3])};
            *(ushort4*)&C[row * 128 + col0 + cg * 4] = o;
        }
    }
}

// C_bf16[M,40] = A[M,128] @ W[128,40]
__global__ __launch_bounds__(256) void gemm2_kernel(const float* __restrict__ A,
                                                    const float* __restrict__ W,
                                                    unsigned short* __restrict__ C, int M) {
    __shared__ __align__(16) float As[64][132];
    __shared__ __align__(16) float Bs[128 * 40];
    const int t = threadIdx.x;
    const int row0 = blockIdx.x * 64;
    #pragma unroll 8
    for (int i = 0; i < 32; ++i) {
        int idx = i * 256 + t;
        int r = idx >> 7, k = idx & 127;
        int row = row0 + r;
        As[r][k] = (row < M) ? A[row * 128 + k] : 0.f;
    }
    for (int idx = t; idx < 128 * 40; idx += 256) Bs[idx] = W[idx];
    __syncthreads();
    const int cg = t & 15, rg = t >> 4;
    float acc[4][4] = {};
    if (cg < 10) {
        for (int k = 0; k < 128; k += 4) {
            float4 a0 = *(const float4*)&As[rg * 4 + 0][k];
            float4 a1 = *(const float4*)&As[rg * 4 + 1][k];
            float4 a2 = *(const float4*)&As[rg * 4 + 2][k];
            float4 a3 = *(const float4*)&As[rg * 4 + 3][k];
            float4 b0 = *(const float4*)&Bs[(k + 0) * 40 + cg * 4];
            float4 b1 = *(const float4*)&Bs[(k + 1) * 40 + cg * 4];
            float4 b2 = *(const float4*)&Bs[(k + 2) * 40 + cg * 4];
            float4 b3 = *(const float4*)&Bs[(k + 3) * 40 + cg * 4];
            float av[4][4] = {{a0.x, a0.y, a0.z, a0.w}, {a1.x, a1.y, a1.z, a1.w},
                              {a2.x, a2.y, a2.z, a2.w}, {a3.x, a3.y, a3.z, a3.w}};
            float bv[4][4] = {{b0.x, b0.y, b0.z, b0.w}, {b1.x, b1.y, b1.z, b1.w},
                              {b2.x, b2.y, b2.z, b2.w}, {b3.x, b3.y, b3.z, b3.w}};
            #pragma unroll
            for (int i = 0; i < 4; ++i)
                #pragma unroll
                for (int kk = 0; kk < 4; ++kk)
                    #pragma unroll
                    for (int j = 0; j < 4; ++j)
                        acc[i][j] += av[i][kk] * bv[kk][j];
        }
        #pragma unroll
        for (int i = 0; i < 4; ++i) {
            int row = row0 + rg * 4 + i;
            if (row < M) {
                ushort4 o = {f2bf(acc[i][0]), f2bf(acc[i][1]), f2bf(acc[i][2]), f2bf(acc[i][3])};
                *(ushort4*)&C[row * 40 + cg * 4] = o;
            }
        }
    }
}

// layer-1 aggregate (bf16 gather, f32 accum) + epilogue (width 128)
__global__ void spmm1_kernel(const int* __restrict__ csc_off, const int* __restrict__ csc_src,
                             const int* __restrict__ out_cnt, const unsigned short* __restrict__ G,
                             const float* __restrict__ b1, float* __restrict__ H) {
    int v = blockIdx.x;
    int f = threadIdx.x;
    int beg = csc_off[v], end = csc_off[v + 1];
    float acc = 0.f;
    int e = beg;
    for (; e + 8 <= end; e += 8) {
        int u0 = csc_src[e + 0], u1 = csc_src[e + 1], u2 = csc_src[e + 2], u3 = csc_src[e + 3];
        int u4 = csc_src[e + 4], u5 = csc_src[e + 5], u6 = csc_src[e + 6], u7 = csc_src[e + 7];
        unsigned short g0 = G[u0 * 128 + f];
        unsigned short g1 = G[u1 * 128 + f];
        unsigned short g2 = G[u2 * 128 + f];
        unsigned short g3 = G[u3 * 128 + f];
        unsigned short g4 = G[u4 * 128 + f];
        unsigned short g5 = G[u5 * 128 + f];
        unsigned short g6 = G[u6 * 128 + f];
        unsigned short g7 = G[u7 * 128 + f];
        acc += ((bf2f(g0) + bf2f(g1)) + (bf2f(g2) + bf2f(g3))) +
               ((bf2f(g4) + bf2f(g5)) + (bf2f(g6) + bf2f(g7)));
    }
    if (e + 4 <= end) {
        int u0 = csc_src[e + 0], u1 = csc_src[e + 1], u2 = csc_src[e + 2], u3 = csc_src[e + 3];
        unsigned short g0 = G[u0 * 128 + f];
        unsigned short g1 = G[u1 * 128 + f];
        unsigned short g2 = G[u2 * 128 + f];
        unsigned short g3 = G[u3 * 128 + f];
        acc += (bf2f(g0) + bf2f(g1)) + (bf2f(g2) + bf2f(g3));
        e += 4;
    }
    for (; e < end; ++e) acc += bf2f(G[csc_src[e] * 128 + f]);
    float rin = 1.f / sqrtf(fmaxf((float)(end - beg), 1.f));
    float rout = 1.f / sqrtf(fmaxf((float)out_cnt[v], 1.f));
    float x = acc * rin + b1[f];
    H[v * 128 + f] = fmaxf(x, 0.f) * rout;
}

// layer-2 aggregate (bf16 gather) + epilogue (width 40)
__global__ void spmm2_kernel(const int* __restrict__ csc_off, const int* __restrict__ csc_src,
                             const unsigned short* __restrict__ G2, const float* __restrict__ b2,
                             float* __restrict__ out) {
    int v = blockIdx.x;
    int f = threadIdx.x;
    int beg = csc_off[v], end = csc_off[v + 1];
    if (f < N_CLASSES) {
        float acc = 0.f;
        int e = beg;
        for (; e + 8 <= end; e += 8) {
            int u0 = csc_src[e + 0], u1 = csc_src[e + 1], u2 = csc_src[e + 2], u3 = csc_src[e + 3];
            int u4 = csc_src[e + 4], u5 = csc_src[e + 5], u6 = csc_src[e + 6], u7 = csc_src[e + 7];
            unsigned short g0 = G2[u0 * N_CLASSES + f];
            unsigned short g1 = G2[u1 * N_CLASSES + f];
            unsigned short g2 = G2[u2 * N_CLASSES + f];
            unsigned short g3 = G2[u3 * N_CLASSES + f];
            unsigned short g4 = G2[u4 * N_CLASSES + f];
            unsigned short g5 = G2[u5 * N_CLASSES + f];
            unsigned short g6 = G2[u6 * N_CLASSES + f];
            unsigned short g7 = G2[u7 * N_CLASSES + f];
            acc += ((bf2f(g0) + bf2f(g1)) + (bf2f(g2) + bf2f(g3))) +
                   ((bf2f(g4) + bf2f(g5)) + (bf2f(g6) + bf2f(g7)));
        }
        if (e + 4 <= end) {
            int u0 = csc_src[e + 0], u1 = csc_src[e + 1], u2 = csc_src[e + 2], u3 = csc_src[e + 3];
            acc += (bf2f(G2[u0 * N_CLASSES + f]) + bf2f(G2[u1 * N_CLASSES + f])) +
                   (bf2f(G2[u2 * N_CLASSES + f]) + bf2f(G2[u3 * N_CLASSES + f]));
            e += 4;
        }
        for (; e < end; ++e) acc += bf2f(G2[csc_src[e] * N_CLASSES + f]);
        float rin = 1.f / sqrtf(fmaxf((float)(end - beg), 1.f));
        out[v * N_CLASSES + f] = acc * rin + b2[f];
    }
}

extern "C" void kernel_launch(void* const* d_in, const int* in_sizes, int n_in,
                              void* d_out, int out_size, void* d_ws, size_t ws_size,
                              hipStream_t stream) {
    const int*   feats = (const int*)d_in[0];
    const int*   src   = (const int*)d_in[1];
    const int*   dst   = (const int*)d_in[2];
    const float* emb   = (const float*)d_in[3];
    const float* W1    = (const float*)d_in[4];
    const float* b1    = (const float*)d_in[5];
    const float* W2    = (const float*)d_in[6];
    const float* b2    = (const float*)d_in[7];
    float* out = (float*)d_out;

    char* w = (char*)d_ws;
    int*   in_rep    = (int*)(w + 0);
    int*   out_rep   = (int*)(w + 1600000);
    int*   cursor    = (int*)(w + 3200000);
    int*   partials  = (int*)(w + 4800000);
    int*   block_off = (int*)(w + 4802048);
    float* hA        = (float*)(w + 0);        // overlays the above
    int*   csc_off   = (int*)(w + 25600000);
    int*   out_cnt   = (int*)(w + 25800448);
    int*   csc_src   = (int*)(w + 26000448);
    unsigned short* hB = (unsigned short*)(w + 29200448);  // bf16 G1 then G2

    zero_int4<<<(200000 + 255) / 256, 256, 0, stream>>>((int4*)w, 200000);
    degree_kernel<<<(N_EDGES / 2 + 255) / 256, 256, 0, stream>>>(src, dst, out_rep, in_rep, N_EDGES);
    part_sums<<<SCAN_BLOCKS, 256, 0, stream>>>(in_rep, partials);
    scan_partials<<<1, 256, 0, stream>>>(partials, block_off, csc_off);
    apply_scan<<<SCAN_BLOCKS, 256, 0, stream>>>(in_rep, out_rep, block_off, csc_off, cursor, out_cnt);
    fill_csc<<<(N_EDGES / 2 + 255) / 256, 256, 0, stream>>>(src, dst, cursor, csc_src, N_EDGES);
    pool_kernel<<<N_NODES, 128, 0, stream>>>(feats, emb, out_cnt, hA);
    gemm1_kernel<<<dim3((N_NODES + 63) / 64, 2), 256, 0, stream>>>(hA, W1, hB, N_NODES);
    spmm1_kernel<<<N_NODES, 128, 0, stream>>>(csc_off, csc_src, out_cnt, hB, b1, hA);
    gemm2_kernel<<<(N_NODES + 63) / 64, 256, 0, stream>>>(hA, W2, hB, N_NODES);
    spmm2_kernel<<<N_NODES, 64, 0, stream>>>(csc_off, csc_src, hB, b2, out);
}

// Round 6
// 401.292 us; speedup vs baseline: 1.4615x; 1.0122x over previous
//
#include <hip/hip_runtime.h>
#include <math.h>

#define N_NODES 50000
#define N_EDGES 800000
#define IN_FEATS 128
#define N_HIDDEN 128
#define N_CLASSES 40
#define SEQ_LEN 20
#define SCAN_BLOCKS 196   // ceil(50000/256)
#define NREP 8
#define DEG_BLOCKS 1563   // ceil(800000 / (256*2)); SAME mapping in K1-degree and K2-fill
#define POOL_BLOCKS 25000 // 2 nodes per 256-thread block
#define GEMM1_BLOCKS 1564 // 782 row tiles x 2 col tiles

// bf16 helpers (RNE)
__device__ inline unsigned short f2bf(float x) {
    union { float f; unsigned int u; } v; v.f = x;
    unsigned int r = v.u + 0x7FFF + ((v.u >> 16) & 1);
    return (unsigned short)(r >> 16);
}
__device__ inline float bf2f(unsigned short b) {
    union { float f; unsigned int u; } v; v.u = ((unsigned int)b) << 16;
    return v.f;
}

// ---------------- workspace layout (bytes) — NO overlays (K1 runs pool
// concurrently with rep-array writers) ----------------
//   in_rep  : 0          int[8*50000]  1.6 MB
//   out_rep : 1600000    int[8*50000]  1.6 MB
//   cursor  : 3200000    int[8*50000]  1.6 MB
//   partials: 4800000    int[256]
//   block_off:4801024    int[256]
//   h0      : 4802560    float[50000*128]  25.6 MB
//   csc_off : 30402560   int[50001]
//   out_cnt : 30602752   int[50000]
//   csc_src : 30802752   int[800000]   3.2 MB
//   G1(bf16): 34002752   ushort[50000*128] 12.8 MB
//   G2(bf16): 46802752   ushort[50000*40]   4.0 MB   -> total ~50.8 MB

__global__ void zero_int4(int4* __restrict__ p, int n4) {
    int i = blockIdx.x * blockDim.x + threadIdx.x;
    if (i < n4) p[i] = make_int4(0, 0, 0, 0);
}

// ===== K1: degree histograms (atomic/fabric-bound) fused with embedding
// mean-pool (gather/BW-bound). Block-level branch; no divergence inside waves.
__global__ __launch_bounds__(256) void deg_pool_kernel(
        const int* __restrict__ src, const int* __restrict__ dst,
        int* __restrict__ out_rep, int* __restrict__ in_rep,
        const int* __restrict__ feats, const float* __restrict__ emb,
        float* __restrict__ h0) {
    int b = blockIdx.x;
    int t = threadIdx.x;
    if (b < DEG_BLOCKS) {
        int gid = b * 256 + t;
        int r = b & (NREP - 1);
        int* orp = out_rep + r * N_NODES;
        int* irp = in_rep + r * N_NODES;
        int e = gid * 2;
        if (e < N_EDGES) {
            atomicAdd(&orp[src[e]], 1);
            atomicAdd(&irp[dst[e]], 1);
        }
        if (e + 1 < N_EDGES) {
            atomicAdd(&orp[src[e + 1]], 1);
            atomicAdd(&irp[dst[e + 1]], 1);
        }
    } else {
        int pb = b - DEG_BLOCKS;
        int v = pb * 2 + (t >> 7);          // 2 nodes per block
        int f = t & 127;
        const int* tk = feats + v * SEQ_LEN;
        float acc = 0.f;
        int cnt = 0;
        #pragma unroll
        for (int s = 0; s < SEQ_LEN; ++s) {
            int tok = tk[s];
            cnt += (tok != 0);
            acc += emb[tok * IN_FEATS + f];  // pad row 0 is all-zero
        }
        h0[v * IN_FEATS + f] = acc / (float)max(cnt, 1);   // rout folded later (gemm1)
    }
}

// ---- 3-phase exclusive scan over summed in-replicas ----
__global__ __launch_bounds__(256) void part_sums(const int* __restrict__ in_rep,
                                                 int* __restrict__ partials) {
    __shared__ int s[256];
    int t = threadIdx.x;
    int i = blockIdx.x * 256 + t;
    int v = 0;
    if (i < N_NODES) {
        #pragma unroll
        for (int r = 0; r < NREP; ++r) v += in_rep[r * N_NODES + i];
    }
    s[t] = v;
    __syncthreads();
    #pragma unroll
    for (int d = 128; d > 0; d >>= 1) {
        if (t < d) s[t] += s[t + d];
        __syncthreads();
    }
    if (t == 0) partials[blockIdx.x] = s[0];
}

__global__ __launch_bounds__(256) void scan_partials(const int* __restrict__ partials,
                                                     int* __restrict__ block_off,
                                                     int* __restrict__ csc_off) {
    __shared__ int s[256];
    int t = threadIdx.x;
    int v = (t < SCAN_BLOCKS) ? partials[t] : 0;
    s[t] = v;
    __syncthreads();
    #pragma unroll
    for (int d = 1; d < 256; d <<= 1) {
        int x = (t >= d) ? s[t - d] : 0;
        __syncthreads();
        s[t] += x;
        __syncthreads();
    }
    block_off[t] = s[t] - v;
    if (t == 255) csc_off[N_NODES] = s[255];
}

__global__ __launch_bounds__(256) void apply_scan(const int* __restrict__ in_rep,
                                                  const int* __restrict__ out_rep,
                                                  const int* __restrict__ block_off,
                                                  int* __restrict__ csc_off,
                                                  int* __restrict__ cursor,
                                                  int* __restrict__ out_cnt) {
    __shared__ int s[256];
    int t = threadIdx.x;
    int i = blockIdx.x * 256 + t;
    int rv[NREP];
    int v = 0;
    if (i < N_NODES) {
        #pragma unroll
        for (int r = 0; r < NREP; ++r) { rv[r] = in_rep[r * N_NODES + i]; v += rv[r]; }
    } else {
        #pragma unroll
        for (int r = 0; r < NREP; ++r) rv[r] = 0;
    }
    s[t] = v;
    __syncthreads();
    #pragma unroll
    for (int d = 1; d < 256; d <<= 1) {
        int x = (t >= d) ? s[t - d] : 0;
        __syncthreads();
        s[t] += x;
        __syncthreads();
    }
    if (i < N_NODES) {
        int o = block_off[blockIdx.x] + s[t] - v;
        csc_off[i] = o;
        int run = o;
        #pragma unroll
        for (int r = 0; r < NREP; ++r) { cursor[r * N_NODES + i] = run; run += rv[r]; }
        int oc = 0;
        #pragma unroll
        for (int r = 0; r < NREP; ++r) oc += out_rep[r * N_NODES + i];
        out_cnt[i] = oc;
    }
}

// ===== K2: CSC fill (atomic-bound) fused with GEMM1 (LDS/VALU-bound).
// G1_bf16[M,128] = (rout ⊙ h0)[M,128] @ W1[128,128]
__global__ __launch_bounds__(256) void fill_gemm1_kernel(
        const int* __restrict__ src, const int* __restrict__ dst,
        int* __restrict__ cursor, int* __restrict__ csc_src,
        const float* __restrict__ A, const float* __restrict__ W,
        const int* __restrict__ out_cnt, unsigned short* __restrict__ C, int M) {
    __shared__ __align__(16) float As[64][132];
    __shared__ __align__(16) float Bs[128][64];
    int b = blockIdx.x;
    const int t = threadIdx.x;
    if (b < DEG_BLOCKS) {
        // fill path — replica mapping identical to K1's degree path
        int gid = b * 256 + t;
        int r = b & (NREP - 1);
        int* cur = cursor + r * N_NODES;
        int e = gid * 2;
        if (e < N_EDGES) {
            int p = atomicAdd(&cur[dst[e]], 1);
            csc_src[p] = src[e];
        }
        if (e + 1 < N_EDGES) {
            int p = atomicAdd(&cur[dst[e + 1]], 1);
            csc_src[p] = src[e + 1];
        }
        return;
    }
    int gb = b - DEG_BLOCKS;
    const int row0 = (gb >> 1) * 64;
    const int col0 = (gb & 1) * 64;
    #pragma unroll 8
    for (int i = 0; i < 32; ++i) {
        int idx = i * 256 + t;
        int r = idx >> 7, k = idx & 127;
        int row = row0 + r;
        As[r][k] = (row < M) ? A[row * 128 + k] : 0.f;
    }
    #pragma unroll 8
    for (int i = 0; i < 32; ++i) {
        int idx = i * 256 + t;
        int k = idx >> 6, c = idx & 63;
        Bs[k][c] = W[k * 128 + col0 + c];
    }
    __syncthreads();
    const int cg = t & 15, rg = t >> 4;
    float acc[4][4] = {};
    for (int k = 0; k < 128; k += 4) {
        float4 a0 = *(const float4*)&As[rg * 4 + 0][k];
        float4 a1 = *(const float4*)&As[rg * 4 + 1][k];
        float4 a2 = *(const float4*)&As[rg * 4 + 2][k];
        float4 a3 = *(const float4*)&As[rg * 4 + 3][k];
        float4 b0 = *(const float4*)&Bs[k + 0][cg * 4];
        float4 b1 = *(const float4*)&Bs[k + 1][cg * 4];
        float4 b2 = *(const float4*)&Bs[k + 2][cg * 4];
        float4 b3 = *(const float4*)&Bs[k + 3][cg * 4];
        float av[4][4] = {{a0.x, a0.y, a0.z, a0.w}, {a1.x, a1.y, a1.z, a1.w},
                          {a2.x, a2.y, a2.z, a2.w}, {a3.x, a3.y, a3.z, a3.w}};
        float bv[4][4] = {{b0.x, b0.y, b0.z, b0.w}, {b1.x, b1.y, b1.z, b1.w},
                          {b2.x, b2.y, b2.z, b2.w}, {b3.x, b3.y, b3.z, b3.w}};
        #pragma unroll
        for (int i = 0; i < 4; ++i)
            #pragma unroll
            for (int kk = 0; kk < 4; ++kk)
                #pragma unroll
                for (int j = 0; j < 4; ++j)
                    acc[i][j] += av[i][kk] * bv[kk][j];
    }
    #pragma unroll
    for (int i = 0; i < 4; ++i) {
        int row = row0 + rg * 4 + i;
        if (row < M) {
            float rout = 1.f / sqrtf(fmaxf((float)out_cnt[row], 1.f));
            ushort4 o = {f2bf(acc[i][0] * rout), f2bf(acc[i][1] * rout),
                         f2bf(acc[i][2] * rout), f2bf(acc[i][3] * rout)};
            *(ushort4*)&C[row * 128 + col0 + cg * 4] = o;
        }
    }
}

// ===== spmm1 + gemm2 fused: h1 row (LDS) -> G2_bf16[v,0:40] = h1 @ W2
__global__ void spmm1g2_kernel(const int* __restrict__ csc_off, const int* __restrict__ csc_src,
                               const int* __restrict__ out_cnt, const unsigned short* __restrict__ G,
                               const float* __restrict__ b1, const float* __restrict__ W2,
                               unsigned short* __restrict__ G2) {
    __shared__ float h1s[128];
    int v = blockIdx.x;
    int f = threadIdx.x;
    int beg = csc_off[v], end = csc_off[v + 1];
    float acc = 0.f;
    int e = beg;
    for (; e + 8 <= end; e += 8) {
        int u0 = csc_src[e + 0], u1 = csc_src[e + 1], u2 = csc_src[e + 2], u3 = csc_src[e + 3];
        int u4 = csc_src[e + 4], u5 = csc_src[e + 5], u6 = csc_src[e + 6], u7 = csc_src[e + 7];
        unsigned short g0 = G[u0 * 128 + f];
        unsigned short g1 = G[u1 * 128 + f];
        unsigned short g2 = G[u2 * 128 + f];
        unsigned short g3 = G[u3 * 128 + f];
        unsigned short g4 = G[u4 * 128 + f];
        unsigned short g5 = G[u5 * 128 + f];
        unsigned short g6 = G[u6 * 128 + f];
        unsigned short g7 = G[u7 * 128 + f];
        acc += ((bf2f(g0) + bf2f(g1)) + (bf2f(g2) + bf2f(g3))) +
               ((bf2f(g4) + bf2f(g5)) + (bf2f(g6) + bf2f(g7)));
    }
    if (e + 4 <= end) {
        int u0 = csc_src[e + 0], u1 = csc_src[e + 1], u2 = csc_src[e + 2], u3 = csc_src[e + 3];
        acc += (bf2f(G[u0 * 128 + f]) + bf2f(G[u1 * 128 + f])) +
               (bf2f(G[u2 * 128 + f]) + bf2f(G[u3 * 128 + f]));
        e += 4;
    }
    for (; e < end; ++e) acc += bf2f(G[csc_src[e] * 128 + f]);
    float rin = 1.f / sqrtf(fmaxf((float)(end - beg), 1.f));
    float rout = 1.f / sqrtf(fmaxf((float)out_cnt[v], 1.f));
    h1s[f] = fmaxf(acc * rin + b1[f], 0.f) * rout;
    __syncthreads();
    if (f < N_CLASSES) {
        float s0 = 0.f, s1 = 0.f, s2 = 0.f, s3 = 0.f;
        #pragma unroll 8
        for (int k = 0; k < 128; k += 4) {
            s0 += h1s[k + 0] * W2[(k + 0) * N_CLASSES + f];
            s1 += h1s[k + 1] * W2[(k + 1) * N_CLASSES + f];
            s2 += h1s[k + 2] * W2[(k + 2) * N_CLASSES + f];
            s3 += h1s[k + 3] * W2[(k + 3) * N_CLASSES + f];
        }
        G2[v * N_CLASSES + f] = f2bf((s0 + s1) + (s2 + s3));
    }
}

// layer-2 aggregate (bf16 gather from 4 MB L2-resident G2) + epilogue
__global__ void spmm2_kernel(const int* __restrict__ csc_off, const int* __restrict__ csc_src,
                             const unsigned short* __restrict__ G2, const float* __restrict__ b2,
                             float* __restrict__ out) {
    int v = blockIdx.x;
    int f = threadIdx.x;
    int beg = csc_off[v], end = csc_off[v + 1];
    if (f < N_CLASSES) {
        float acc = 0.f;
        int e = beg;
        for (; e + 8 <= end; e += 8) {
            int u0 = csc_src[e + 0], u1 = csc_src[e + 1], u2 = csc_src[e + 2], u3 = csc_src[e + 3];
            int u4 = csc_src[e + 4], u5 = csc_src[e + 5], u6 = csc_src[e + 6], u7 = csc_src[e + 7];
            acc += ((bf2f(G2[u0 * N_CLASSES + f]) + bf2f(G2[u1 * N_CLASSES + f])) +
                    (bf2f(G2[u2 * N_CLASSES + f]) + bf2f(G2[u3 * N_CLASSES + f]))) +
                   ((bf2f(G2[u4 * N_CLASSES + f]) + bf2f(G2[u5 * N_CLASSES + f])) +
                    (bf2f(G2[u6 * N_CLASSES + f]) + bf2f(G2[u7 * N_CLASSES + f])));
        }
        if (e + 4 <= end) {
            int u0 = csc_src[e + 0], u1 = csc_src[e + 1], u2 = csc_src[e + 2], u3 = csc_src[e + 3];
            acc += (bf2f(G2[u0 * N_CLASSES + f]) + bf2f(G2[u1 * N_CLASSES + f])) +
                   (bf2f(G2[u2 * N_CLASSES + f]) + bf2f(G2[u3 * N_CLASSES + f]));
            e += 4;
        }
        for (; e < end; ++e) acc += bf2f(G2[csc_src[e] * N_CLASSES + f]);
        float rin = 1.f / sqrtf(fmaxf((float)(end - beg), 1.f));
        out[v * N_CLASSES + f] = acc * rin + b2[f];
    }
}

extern "C" void kernel_launch(void* const* d_in, const int* in_sizes, int n_in,
                              void* d_out, int out_size, void* d_ws, size_t ws_size,
                              hipStream_t stream) {
    const int*   feats = (const int*)d_in[0];
    const int*   src   = (const int*)d_in[1];
    const int*   dst   = (const int*)d_in[2];
    const float* emb   = (const float*)d_in[3];
    const float* W1    = (const float*)d_in[4];
    const float* b1    = (const float*)d_in[5];
    const float* W2    = (const float*)d_in[6];
    const float* b2    = (const float*)d_in[7];
    float* out = (float*)d_out;

    char* w = (char*)d_ws;
    int*   in_rep    = (int*)(w + 0);
    int*   out_rep   = (int*)(w + 1600000);
    int*   cursor    = (int*)(w + 3200000);
    int*   partials  = (int*)(w + 4800000);
    int*   block_off = (int*)(w + 4801024);
    float* h0        = (float*)(w + 4802560);
    int*   csc_off   = (int*)(w + 30402560);
    int*   out_cnt   = (int*)(w + 30602752);
    int*   csc_src   = (int*)(w + 30802752);
    unsigned short* G1 = (unsigned short*)(w + 34002752);
    unsigned short* G2 = (unsigned short*)(w + 46802752);

    // 1) zero replica counters (in_rep + out_rep = 3.2 MB)
    zero_int4<<<(200000 + 255) / 256, 256, 0, stream>>>((int4*)w, 200000);
    // 2) K1: degree histograms (fabric-atomic) ∥ embedding mean-pool (gather)
    deg_pool_kernel<<<DEG_BLOCKS + POOL_BLOCKS, 256, 0, stream>>>(
        src, dst, out_rep, in_rep, feats, emb, h0);
    // 3) 3-phase exclusive scan -> csc_off / per-replica cursors / out_cnt
    part_sums<<<SCAN_BLOCKS, 256, 0, stream>>>(in_rep, partials);
    scan_partials<<<1, 256, 0, stream>>>(partials, block_off, csc_off);
    apply_scan<<<SCAN_BLOCKS, 256, 0, stream>>>(in_rep, out_rep, block_off, csc_off, cursor, out_cnt);
    // 4) K2: CSC fill (fabric-atomic) ∥ GEMM1 (+rout fold, bf16 out)
    fill_gemm1_kernel<<<DEG_BLOCKS + GEMM1_BLOCKS, 256, 0, stream>>>(
        src, dst, cursor, csc_src, h0, W1, out_cnt, G1, N_NODES);
    // 5) spmm1 + gemm2 fused -> G2 (bf16, 4 MB)
    spmm1g2_kernel<<<N_NODES, 128, 0, stream>>>(csc_off, csc_src, out_cnt, G1, b1, W2, G2);
    // 6) out = agg(G2)*rin + b2
    spmm2_kernel<<<N_NODES, 64, 0, stream>>>(csc_off, csc_src, G2, b2, out);
}

// Round 7
// 315.757 us; speedup vs baseline: 1.8575x; 1.2709x over previous
//
#include <hip/hip_runtime.h>
#include <math.h>

#define N_NODES 50000
#define N_EDGES 800000
#define IN_FEATS 128
#define N_HIDDEN 128
#define N_CLASSES 40
#define SEQ_LEN 20
#define BUCKET_CAP 64     // P(in_deg >= 64 | Poisson(16)) ~ 1e-18; guarded anyway
#define EDGE_BLOCKS 1563  // ceil(800000 / (256*2))
#define POOL_BLOCKS 25000 // 2 nodes per 256-thread block
#define K1_BLOCKS (EDGE_BLOCKS + POOL_BLOCKS)   // 26563; edge blocks at b%17==0

// bf16 helpers (RNE)
__device__ inline unsigned short f2bf(float x) {
    union { float f; unsigned int u; } v; v.f = x;
    unsigned int r = v.u + 0x7FFF + ((v.u >> 16) & 1);
    return (unsigned short)(r >> 16);
}
__device__ inline float bf2f(unsigned short b) {
    union { float f; unsigned int u; } v; v.u = ((unsigned int)b) << 16;
    return v.f;
}

// ---------------- workspace layout (bytes) ----------------
//   in_cnt : 0         int[50000]          (zeroed)
//   out_cnt: 200704    int[50000]          (zeroed; contiguous with in_cnt region)
//   bucket : 401408    int[50000*64]  12.8 MB
//   h0     : 13201408  float[50000*128] 25.6 MB
//   G1     : 38801408  ushort[50000*128] 12.8 MB (bf16)
//   G2     : 51601408  ushort[50000*40]   4.0 MB (bf16)   total ~55.6 MB

__global__ void zero_int4(int4* __restrict__ p, int n4) {
    int i = blockIdx.x * blockDim.x + threadIdx.x;
    if (i < n4) p[i] = make_int4(0, 0, 0, 0);
}

// ===== K1: single-pass bucket-CSC build + out-degree histogram (fabric-atomic)
// interleaved with embedding mean-pool (L2/L3 gather). Both paths LDS-free ->
// full occupancy for each. Edge blocks are b%17==0 so atomic traffic trickles
// alongside gather traffic instead of front-loading.
__global__ __launch_bounds__(256) void build_pool_kernel(
        const int* __restrict__ src, const int* __restrict__ dst,
        int* __restrict__ in_cnt, int* __restrict__ out_cnt, int* __restrict__ bucket,
        const int* __restrict__ feats, const float* __restrict__ emb,
        float* __restrict__ h0) {
    int b = blockIdx.x;
    int t = threadIdx.x;
    if (b % 17 == 0) {
        // ---- edge path: 2 edges/thread, vectorized int2 loads
        int gid = (b / 17) * 256 + t;
        if (gid < N_EDGES / 2) {
            int2 s2 = ((const int2*)src)[gid];
            int2 d2 = ((const int2*)dst)[gid];
            int p0 = atomicAdd(&in_cnt[d2.x], 1);
            if (p0 < BUCKET_CAP) bucket[d2.x * BUCKET_CAP + p0] = s2.x;
            atomicAdd(&out_cnt[s2.x], 1);
            int p1 = atomicAdd(&in_cnt[d2.y], 1);
            if (p1 < BUCKET_CAP) bucket[d2.y * BUCKET_CAP + p1] = s2.y;
            atomicAdd(&out_cnt[s2.y], 1);
        }
    } else {
        // ---- pool path: 2 nodes per block, 128 threads each
        int pb = b - b / 17 - 1;
        int v = pb * 2 + (t >> 7);
        int f = t & 127;
        const int* tk = feats + v * SEQ_LEN;
        float acc = 0.f;
        int cnt = 0;
        #pragma unroll
        for (int s = 0; s < SEQ_LEN; ++s) {
            int tok = tk[s];
            cnt += (tok != 0);
            acc += emb[tok * IN_FEATS + f];   // pad row 0 is all-zero
        }
        h0[v * IN_FEATS + f] = acc / (float)max(cnt, 1);  // rout folded into gemm1
    }
}

// G1_bf16[M,128] = (rout ⊙ h0)[M,128] @ W1[128,128]; 64x64 tile, 4x4/thread
__global__ __launch_bounds__(256) void gemm1_kernel(const float* __restrict__ A,
                                                    const float* __restrict__ W,
                                                    const int* __restrict__ out_cnt,
                                                    unsigned short* __restrict__ C, int M) {
    __shared__ __align__(16) float As[64][132];
    __shared__ __align__(16) float Bs[128][64];
    const int t = threadIdx.x;
    const int row0 = blockIdx.x * 64;
    const int col0 = blockIdx.y * 64;
    #pragma unroll 8
    for (int i = 0; i < 32; ++i) {
        int idx = i * 256 + t;
        int r = idx >> 7, k = idx & 127;
        int row = row0 + r;
        As[r][k] = (row < M) ? A[row * 128 + k] : 0.f;
    }
    #pragma unroll 8
    for (int i = 0; i < 32; ++i) {
        int idx = i * 256 + t;
        int k = idx >> 6, c = idx & 63;
        Bs[k][c] = W[k * 128 + col0 + c];
    }
    __syncthreads();
    const int cg = t & 15, rg = t >> 4;
    float acc[4][4] = {};
    for (int k = 0; k < 128; k += 4) {
        float4 a0 = *(const float4*)&As[rg * 4 + 0][k];
        float4 a1 = *(const float4*)&As[rg * 4 + 1][k];
        float4 a2 = *(const float4*)&As[rg * 4 + 2][k];
        float4 a3 = *(const float4*)&As[rg * 4 + 3][k];
        float4 b0 = *(const float4*)&Bs[k + 0][cg * 4];
        float4 b1 = *(const float4*)&Bs[k + 1][cg * 4];
        float4 b2 = *(const float4*)&Bs[k + 2][cg * 4];
        float4 b3 = *(const float4*)&Bs[k + 3][cg * 4];
        float av[4][4] = {{a0.x, a0.y, a0.z, a0.w}, {a1.x, a1.y, a1.z, a1.w},
                          {a2.x, a2.y, a2.z, a2.w}, {a3.x, a3.y, a3.z, a3.w}};
        float bv[4][4] = {{b0.x, b0.y, b0.z, b0.w}, {b1.x, b1.y, b1.z, b1.w},
                          {b2.x, b2.y, b2.z, b2.w}, {b3.x, b3.y, b3.z, b3.w}};
        #pragma unroll
        for (int i = 0; i < 4; ++i)
            #pragma unroll
            for (int kk = 0; kk < 4; ++kk)
                #pragma unroll
                for (int j = 0; j < 4; ++j)
                    acc[i][j] += av[i][kk] * bv[kk][j];
    }
    #pragma unroll
    for (int i = 0; i < 4; ++i) {
        int row = row0 + rg * 4 + i;
        if (row < M) {
            float rout = 1.f / sqrtf(fmaxf((float)out_cnt[row], 1.f));
            ushort4 o = {f2bf(acc[i][0] * rout), f2bf(acc[i][1] * rout),
                         f2bf(acc[i][2] * rout), f2bf(acc[i][3] * rout)};
            *(ushort4*)&C[row * 128 + col0 + cg * 4] = o;
        }
    }
}

// ===== spmm1 + gemm2 fused: bucket-gather G1 -> h1 (LDS) -> G2 = h1 @ W2
__global__ void spmm1g2_kernel(const int* __restrict__ in_cnt, const int* __restrict__ out_cnt,
                               const int* __restrict__ bucket, const unsigned short* __restrict__ G,
                               const float* __restrict__ b1, const float* __restrict__ W2,
                               unsigned short* __restrict__ G2) {
    __shared__ float h1s[128];
    int v = blockIdx.x;
    int f = threadIdx.x;
    int cnt = in_cnt[v];
    int n = min(cnt, BUCKET_CAP);
    const int* bk = bucket + v * BUCKET_CAP;
    float acc = 0.f;
    int e = 0;
    for (; e + 8 <= n; e += 8) {
        int u0 = bk[e + 0], u1 = bk[e + 1], u2 = bk[e + 2], u3 = bk[e + 3];
        int u4 = bk[e + 4], u5 = bk[e + 5], u6 = bk[e + 6], u7 = bk[e + 7];
        unsigned short g0 = G[u0 * 128 + f];
        unsigned short g1 = G[u1 * 128 + f];
        unsigned short g2 = G[u2 * 128 + f];
        unsigned short g3 = G[u3 * 128 + f];
        unsigned short g4 = G[u4 * 128 + f];
        unsigned short g5 = G[u5 * 128 + f];
        unsigned short g6 = G[u6 * 128 + f];
        unsigned short g7 = G[u7 * 128 + f];
        acc += ((bf2f(g0) + bf2f(g1)) + (bf2f(g2) + bf2f(g3))) +
               ((bf2f(g4) + bf2f(g5)) + (bf2f(g6) + bf2f(g7)));
    }
    if (e + 4 <= n) {
        int u0 = bk[e + 0], u1 = bk[e + 1], u2 = bk[e + 2], u3 = bk[e + 3];
        acc += (bf2f(G[u0 * 128 + f]) + bf2f(G[u1 * 128 + f])) +
               (bf2f(G[u2 * 128 + f]) + bf2f(G[u3 * 128 + f]));
        e += 4;
    }
    for (; e < n; ++e) acc += bf2f(G[bk[e] * 128 + f]);
    float rin = 1.f / sqrtf(fmaxf((float)cnt, 1.f));
    float rout = 1.f / sqrtf(fmaxf((float)out_cnt[v], 1.f));
    h1s[f] = fmaxf(acc * rin + b1[f], 0.f) * rout;
    __syncthreads();
    if (f < N_CLASSES) {
        float s0 = 0.f, s1 = 0.f, s2 = 0.f, s3 = 0.f;
        #pragma unroll 8
        for (int k = 0; k < 128; k += 4) {
            s0 += h1s[k + 0] * W2[(k + 0) * N_CLASSES + f];
            s1 += h1s[k + 1] * W2[(k + 1) * N_CLASSES + f];
            s2 += h1s[k + 2] * W2[(k + 2) * N_CLASSES + f];
            s3 += h1s[k + 3] * W2[(k + 3) * N_CLASSES + f];
        }
        G2[v * N_CLASSES + f] = f2bf((s0 + s1) + (s2 + s3));
    }
}

// layer-2 aggregate (bf16 bucket-gather) + epilogue
__global__ void spmm2_kernel(const int* __restrict__ in_cnt, const int* __restrict__ bucket,
                             const unsigned short* __restrict__ G2, const float* __restrict__ b2,
                             float* __restrict__ out) {
    int v = blockIdx.x;
    int f = threadIdx.x;
    int cnt = in_cnt[v];
    int n = min(cnt, BUCKET_CAP);
    const int* bk = bucket + v * BUCKET_CAP;
    if (f < N_CLASSES) {
        float acc = 0.f;
        int e = 0;
        for (; e + 8 <= n; e += 8) {
            int u0 = bk[e + 0], u1 = bk[e + 1], u2 = bk[e + 2], u3 = bk[e + 3];
            int u4 = bk[e + 4], u5 = bk[e + 5], u6 = bk[e + 6], u7 = bk[e + 7];
            acc += ((bf2f(G2[u0 * N_CLASSES + f]) + bf2f(G2[u1 * N_CLASSES + f])) +
                    (bf2f(G2[u2 * N_CLASSES + f]) + bf2f(G2[u3 * N_CLASSES + f]))) +
                   ((bf2f(G2[u4 * N_CLASSES + f]) + bf2f(G2[u5 * N_CLASSES + f])) +
                    (bf2f(G2[u6 * N_CLASSES + f]) + bf2f(G2[u7 * N_CLASSES + f])));
        }
        if (e + 4 <= n) {
            int u0 = bk[e + 0], u1 = bk[e + 1], u2 = bk[e + 2], u3 = bk[e + 3];
            acc += (bf2f(G2[u0 * N_CLASSES + f]) + bf2f(G2[u1 * N_CLASSES + f])) +
                   (bf2f(G2[u2 * N_CLASSES + f]) + bf2f(G2[u3 * N_CLASSES + f]));
            e += 4;
        }
        for (; e < n; ++e) acc += bf2f(G2[bk[e] * N_CLASSES + f]);
        float rin = 1.f / sqrtf(fmaxf((float)cnt, 1.f));
        out[v * N_CLASSES + f] = acc * rin + b2[f];
    }
}

extern "C" void kernel_launch(void* const* d_in, const int* in_sizes, int n_in,
                              void* d_out, int out_size, void* d_ws, size_t ws_size,
                              hipStream_t stream) {
    const int*   feats = (const int*)d_in[0];
    const int*   src   = (const int*)d_in[1];
    const int*   dst   = (const int*)d_in[2];
    const float* emb   = (const float*)d_in[3];
    const float* W1    = (const float*)d_in[4];
    const float* b1    = (const float*)d_in[5];
    const float* W2    = (const float*)d_in[6];
    const float* b2    = (const float*)d_in[7];
    float* out = (float*)d_out;

    char* w = (char*)d_ws;
    int*   in_cnt  = (int*)(w + 0);
    int*   out_cnt = (int*)(w + 200704);
    int*   bucket  = (int*)(w + 401408);
    float* h0      = (float*)(w + 13201408);
    unsigned short* G1 = (unsigned short*)(w + 38801408);
    unsigned short* G2 = (unsigned short*)(w + 51601408);

    // 1) zero in_cnt + out_cnt (contiguous 401408 B = 100352 ints = 25088 int4)
    zero_int4<<<(25088 + 255) / 256, 256, 0, stream>>>((int4*)w, 25088);
    // 2) K1: bucket-CSC build + out-degree (atomics) interleaved with mean-pool
    build_pool_kernel<<<K1_BLOCKS, 256, 0, stream>>>(
        src, dst, in_cnt, out_cnt, bucket, feats, emb, h0);
    // 3) G1 = (rout ⊙ h0) @ W1, bf16 out
    gemm1_kernel<<<dim3(782, 2), 256, 0, stream>>>(h0, W1, out_cnt, G1, N_NODES);
    // 4) spmm1 + gemm2 fused -> G2 (bf16, 4 MB)
    spmm1g2_kernel<<<N_NODES, 128, 0, stream>>>(in_cnt, out_cnt, bucket, G1, b1, W2, G2);
    // 5) out = agg(G2)*rin + b2
    spmm2_kernel<<<N_NODES, 64, 0, stream>>>(in_cnt, bucket, G2, b2, out);
}

// Round 9
// 313.983 us; speedup vs baseline: 1.8680x; 1.0057x over previous
//
#include <hip/hip_runtime.h>
#include <math.h>

#define N_NODES 50000
#define N_EDGES 800000
#define IN_FEATS 128
#define N_HIDDEN 128
#define N_CLASSES 40
#define SEQ_LEN 20
#define VOCAB 32000
#define BUCKET_CAP 64     // P(in_deg >= 64 | Poisson(16)) ~ 1e-18; guarded anyway
#define EDGE_BLOCKS 1563  // ceil(800000 / (256*2))
#define POOL_BLOCKS 12500 // 4 nodes per 256-thread block
#define K1_BLOCKS (EDGE_BLOCKS + POOL_BLOCKS)   // 14063; edge blocks at b%9==0

// bf16 helpers (RNE)
__device__ inline unsigned short f2bf(float x) {
    union { float f; unsigned int u; } v; v.f = x;
    unsigned int r = v.u + 0x7FFF + ((v.u >> 16) & 1);
    return (unsigned short)(r >> 16);
}
__device__ inline float bf2f(unsigned short b) {
    union { float f; unsigned int u; } v; v.u = ((unsigned int)b) << 16;
    return v.f;
}

// ---------------- workspace layout (bytes) ----------------
//   in_cnt : 0         int[50000]          (zeroed)
//   out_cnt: 200704    int[50000]          (zeroed)
//   bucket : 401408    int[50000*64]   12.8 MB
//   h0     : 13201408  float[50000*128] 25.6 MB
//   G1     : 38801408  ushort[50000*128] 12.8 MB (bf16)
//     emb_bf OVERLAYS G1 (ushort[32000*128] = 8.19 MB): emb_bf is dead after
//     build_pool; gemm1 writes G1 afterwards. Sequential kernels -> safe.
//   G2     : 51601408  ushort[50000*40]   4.0 MB (bf16)   total ~55.6 MB

__global__ void zero_int4(int4* __restrict__ p, int n4) {
    int i = blockIdx.x * blockDim.x + threadIdx.x;
    if (i < n4) p[i] = make_int4(0, 0, 0, 0);
}

// f32 emb table -> bf16 (RNE); 4 elems/thread
__global__ void emb_cvt(const float4* __restrict__ in, ushort4* __restrict__ outv, int n4) {
    int i = blockIdx.x * blockDim.x + threadIdx.x;
    if (i < n4) {
        float4 x = in[i];
        ushort4 o = {f2bf(x.x), f2bf(x.y), f2bf(x.z), f2bf(x.w)};
        outv[i] = o;
    }
}

// ===== K1: single-pass bucket-CSC build + out-degree histogram (fabric-atomic)
// interleaved (b%9==0) with embedding mean-pool (bf16 gather, ushort2/lane).
__global__ __launch_bounds__(256) void build_pool_kernel(
        const int* __restrict__ src, const int* __restrict__ dst,
        int* __restrict__ in_cnt, int* __restrict__ out_cnt, int* __restrict__ bucket,
        const int* __restrict__ feats, const unsigned short* __restrict__ emb_bf,
        float* __restrict__ h0) {
    int b = blockIdx.x;
    int t = threadIdx.x;
    if (b % 9 == 0) {
        // ---- edge path: 2 edges/thread, vectorized int2 loads
        int gid = (b / 9) * 256 + t;
        if (gid < N_EDGES / 2) {
            int2 s2 = ((const int2*)src)[gid];
            int2 d2 = ((const int2*)dst)[gid];
            int p0 = atomicAdd(&in_cnt[d2.x], 1);
            if (p0 < BUCKET_CAP) bucket[d2.x * BUCKET_CAP + p0] = s2.x;
            atomicAdd(&out_cnt[s2.x], 1);
            int p1 = atomicAdd(&in_cnt[d2.y], 1);
            if (p1 < BUCKET_CAP) bucket[d2.y * BUCKET_CAP + p1] = s2.y;
            atomicAdd(&out_cnt[s2.y], 1);
        }
    } else {
        // ---- pool path: 4 nodes/block, 64 lanes span 128 feats via ushort2
        int pb = b - b / 9 - 1;
        int v = pb * 4 + (t >> 6);
        int lane = t & 63;
        const int* tk = feats + v * SEQ_LEN;
        const ushort2* ev = (const ushort2*)emb_bf;
        float a0 = 0.f, a1 = 0.f;
        int cnt = 0;
        #pragma unroll
        for (int s = 0; s < SEQ_LEN; ++s) {
            int tok = tk[s];
            cnt += (tok != 0);
            ushort2 g = ev[tok * 64 + lane];   // pad row 0 is all-zero
            a0 += bf2f(g.x);
            a1 += bf2f(g.y);
        }
        float sc = 1.f / (float)max(cnt, 1);   // rout folded into gemm1
        ((float2*)h0)[v * 64 + lane] = make_float2(a0 * sc, a1 * sc);
    }
}

// G1_bf16[M,128] = (rout ⊙ h0)[M,128] @ W1[128,128]; 64x64 tile, 4x4/thread
__global__ __launch_bounds__(256) void gemm1_kernel(const float* __restrict__ A,
                                                    const float* __restrict__ W,
                                                    const int* __restrict__ out_cnt,
                                                    unsigned short* __restrict__ C, int M) {
    __shared__ __align__(16) float As[64][132];
    __shared__ __align__(16) float Bs[128][64];
    const int t = threadIdx.x;
    const int row0 = blockIdx.x * 64;
    const int col0 = blockIdx.y * 64;
    #pragma unroll 8
    for (int i = 0; i < 32; ++i) {
        int idx = i * 256 + t;
        int r = idx >> 7, k = idx & 127;
        int row = row0 + r;
        As[r][k] = (row < M) ? A[row * 128 + k] : 0.f;
    }
    #pragma unroll 8
    for (int i = 0; i < 32; ++i) {
        int idx = i * 256 + t;
        int k = idx >> 6, c = idx & 63;
        Bs[k][c] = W[k * 128 + col0 + c];
    }
    __syncthreads();
    const int cg = t & 15, rg = t >> 4;
    float acc[4][4] = {};
    for (int k = 0; k < 128; k += 4) {
        float4 a0 = *(const float4*)&As[rg * 4 + 0][k];
        float4 a1 = *(const float4*)&As[rg * 4 + 1][k];
        float4 a2 = *(const float4*)&As[rg * 4 + 2][k];
        float4 a3 = *(const float4*)&As[rg * 4 + 3][k];
        float4 b0 = *(const float4*)&Bs[k + 0][cg * 4];
        float4 b1 = *(const float4*)&Bs[k + 1][cg * 4];
        float4 b2 = *(const float4*)&Bs[k + 2][cg * 4];
        float4 b3 = *(const float4*)&Bs[k + 3][cg * 4];
        float av[4][4] = {{a0.x, a0.y, a0.z, a0.w}, {a1.x, a1.y, a1.z, a1.w},
                          {a2.x, a2.y, a2.z, a2.w}, {a3.x, a3.y, a3.z, a3.w}};
        float bv[4][4] = {{b0.x, b0.y, b0.z, b0.w}, {b1.x, b1.y, b1.z, b1.w},
                          {b2.x, b2.y, b2.z, b2.w}, {b3.x, b3.y, b3.z, b3.w}};
        #pragma unroll
        for (int i = 0; i < 4; ++i)
            #pragma unroll
            for (int kk = 0; kk < 4; ++kk)
                #pragma unroll
                for (int j = 0; j < 4; ++j)
                    acc[i][j] += av[i][kk] * bv[kk][j];
    }
    #pragma unroll
    for (int i = 0; i < 4; ++i) {
        int row = row0 + rg * 4 + i;
        if (row < M) {
            float rout = 1.f / sqrtf(fmaxf((float)out_cnt[row], 1.f));
            ushort4 o = {f2bf(acc[i][0] * rout), f2bf(acc[i][1] * rout),
                         f2bf(acc[i][2] * rout), f2bf(acc[i][3] * rout)};
            *(ushort4*)&C[row * 128 + col0 + cg * 4] = o;
        }
    }
}

// ===== spmm1 + gemm2 fused: 4 nodes/block, ushort2 gathers; h1 (LDS) -> G2
__global__ __launch_bounds__(256) void spmm1g2_kernel(
        const int* __restrict__ in_cnt, const int* __restrict__ out_cnt,
        const int* __restrict__ bucket, const unsigned short* __restrict__ G,
        const float* __restrict__ b1, const float* __restrict__ W2,
        unsigned short* __restrict__ G2) {
    __shared__ float h1s[4][128];
    int t = threadIdx.x;
    int node = t >> 6, lane = t & 63;
    int v = blockIdx.x * 4 + node;
    int cnt = in_cnt[v];
    int n = min(cnt, BUCKET_CAP);
    const int* bk = bucket + v * BUCKET_CAP;
    const ushort2* Gv = (const ushort2*)G;
    float a0 = 0.f, a1 = 0.f;
    int e = 0;
    for (; e + 8 <= n; e += 8) {
        int u0 = bk[e + 0], u1 = bk[e + 1], u2 = bk[e + 2], u3 = bk[e + 3];
        int u4 = bk[e + 4], u5 = bk[e + 5], u6 = bk[e + 6], u7 = bk[e + 7];
        ushort2 g0 = Gv[u0 * 64 + lane];
        ushort2 g1 = Gv[u1 * 64 + lane];
        ushort2 g2 = Gv[u2 * 64 + lane];
        ushort2 g3 = Gv[u3 * 64 + lane];
        ushort2 g4 = Gv[u4 * 64 + lane];
        ushort2 g5 = Gv[u5 * 64 + lane];
        ushort2 g6 = Gv[u6 * 64 + lane];
        ushort2 g7 = Gv[u7 * 64 + lane];
        a0 += ((bf2f(g0.x) + bf2f(g1.x)) + (bf2f(g2.x) + bf2f(g3.x))) +
              ((bf2f(g4.x) + bf2f(g5.x)) + (bf2f(g6.x) + bf2f(g7.x)));
        a1 += ((bf2f(g0.y) + bf2f(g1.y)) + (bf2f(g2.y) + bf2f(g3.y))) +
              ((bf2f(g4.y) + bf2f(g5.y)) + (bf2f(g6.y) + bf2f(g7.y)));
    }
    if (e + 4 <= n) {
        int u0 = bk[e + 0], u1 = bk[e + 1], u2 = bk[e + 2], u3 = bk[e + 3];
        ushort2 g0 = Gv[u0 * 64 + lane];
        ushort2 g1 = Gv[u1 * 64 + lane];
        ushort2 g2 = Gv[u2 * 64 + lane];
        ushort2 g3 = Gv[u3 * 64 + lane];
        a0 += (bf2f(g0.x) + bf2f(g1.x)) + (bf2f(g2.x) + bf2f(g3.x));
        a1 += (bf2f(g0.y) + bf2f(g1.y)) + (bf2f(g2.y) + bf2f(g3.y));
        e += 4;
    }
    for (; e < n; ++e) {
        ushort2 g = Gv[bk[e] * 64 + lane];
        a0 += bf2f(g.x);
        a1 += bf2f(g.y);
    }
    float rin = 1.f / sqrtf(fmaxf((float)cnt, 1.f));
    float rout = 1.f / sqrtf(fmaxf((float)out_cnt[v], 1.f));
    float2 bb = ((const float2*)b1)[lane];
    h1s[node][2 * lane + 0] = fmaxf(a0 * rin + bb.x, 0.f) * rout;
    h1s[node][2 * lane + 1] = fmaxf(a1 * rin + bb.y, 0.f) * rout;
    __syncthreads();
    if (lane < N_CLASSES) {
        const float* hn = h1s[node];
        float s0 = 0.f, s1 = 0.f, s2 = 0.f, s3 = 0.f;
        #pragma unroll 8
        for (int k = 0; k < 128; k += 4) {
            s0 += hn[k + 0] * W2[(k + 0) * N_CLASSES + lane];
            s1 += hn[k + 1] * W2[(k + 1) * N_CLASSES + lane];
            s2 += hn[k + 2] * W2[(k + 2) * N_CLASSES + lane];
            s3 += hn[k + 3] * W2[(k + 3) * N_CLASSES + lane];
        }
        G2[v * N_CLASSES + lane] = f2bf((s0 + s1) + (s2 + s3));
    }
}

// layer-2 aggregate (bf16 bucket-gather) + epilogue; 4 nodes/block
__global__ __launch_bounds__(256) void spmm2_kernel(
        const int* __restrict__ in_cnt, const int* __restrict__ bucket,
        const unsigned short* __restrict__ G2, const float* __restrict__ b2,
        float* __restrict__ out) {
    int t = threadIdx.x;
    int node = t >> 6, f = t & 63;
    int v = blockIdx.x * 4 + node;
    int cnt = in_cnt[v];
    int n = min(cnt, BUCKET_CAP);
    const int* bk = bucket + v * BUCKET_CAP;
    if (f < N_CLASSES) {
        float acc = 0.f;
        int e = 0;
        for (; e + 8 <= n; e += 8) {
            int u0 = bk[e + 0], u1 = bk[e + 1], u2 = bk[e + 2], u3 = bk[e + 3];
            int u4 = bk[e + 4], u5 = bk[e + 5], u6 = bk[e + 6], u7 = bk[e + 7];
            acc += ((bf2f(G2[u0 * N_CLASSES + f]) + bf2f(G2[u1 * N_CLASSES + f])) +
                    (bf2f(G2[u2 * N_CLASSES + f]) + bf2f(G2[u3 * N_CLASSES + f]))) +
                   ((bf2f(G2[u4 * N_CLASSES + f]) + bf2f(G2[u5 * N_CLASSES + f])) +
                    (bf2f(G2[u6 * N_CLASSES + f]) + bf2f(G2[u7 * N_CLASSES + f])));
        }
        if (e + 4 <= n) {
            int u0 = bk[e + 0], u1 = bk[e + 1], u2 = bk[e + 2], u3 = bk[e + 3];
            acc += (bf2f(G2[u0 * N_CLASSES + f]) + bf2f(G2[u1 * N_CLASSES + f])) +
                   (bf2f(G2[u2 * N_CLASSES + f]) + bf2f(G2[u3 * N_CLASSES + f]));
            e += 4;
        }
        for (; e < n; ++e) acc += bf2f(G2[bk[e] * N_CLASSES + f]);
        float rin = 1.f / sqrtf(fmaxf((float)cnt, 1.f));
        out[v * N_CLASSES + f] = acc * rin + b2[f];
    }
}

extern "C" void kernel_launch(void* const* d_in, const int* in_sizes, int n_in,
                              void* d_out, int out_size, void* d_ws, size_t ws_size,
                              hipStream_t stream) {
    const int*   feats = (const int*)d_in[0];
    const int*   src   = (const int*)d_in[1];
    const int*   dst   = (const int*)d_in[2];
    const float* emb   = (const float*)d_in[3];
    const float* W1    = (const float*)d_in[4];
    const float* b1    = (const float*)d_in[5];
    const float* W2    = (const float*)d_in[6];
    const float* b2    = (const float*)d_in[7];
    float* out = (float*)d_out;

    char* w = (char*)d_ws;
    int*   in_cnt  = (int*)(w + 0);
    int*   out_cnt = (int*)(w + 200704);
    int*   bucket  = (int*)(w + 401408);
    float* h0      = (float*)(w + 13201408);
    unsigned short* G1     = (unsigned short*)(w + 38801408);
    unsigned short* emb_bf = (unsigned short*)(w + 38801408);  // overlays G1 (dead before gemm1)
    unsigned short* G2     = (unsigned short*)(w + 51601408);

    // 1) zero in_cnt + out_cnt
    zero_int4<<<(25088 + 255) / 256, 256, 0, stream>>>((int4*)w, 25088);
    // 2) emb f32 -> bf16 (halves pool gather traffic; 8 MB table L2-resides better)
    emb_cvt<<<(VOCAB * IN_FEATS / 4 + 255) / 256, 256, 0, stream>>>(
        (const float4*)emb, (ushort4*)emb_bf, VOCAB * IN_FEATS / 4);
    // 3) K1: bucket-CSC build + out-degree (atomics) interleaved with mean-pool
    build_pool_kernel<<<K1_BLOCKS, 256, 0, stream>>>(
        src, dst, in_cnt, out_cnt, bucket, feats, emb_bf, h0);
    // 4) G1 = (rout ⊙ h0) @ W1, bf16 out (overwrites emb_bf region)
    gemm1_kernel<<<dim3(782, 2), 256, 0, stream>>>(h0, W1, out_cnt, G1, N_NODES);
    // 5) spmm1 + gemm2 fused -> G2 (bf16, 4 MB)
    spmm1g2_kernel<<<POOL_BLOCKS, 256, 0, stream>>>(in_cnt, out_cnt, bucket, G1, b1, W2, G2);
    // 6) out = agg(G2)*rin + b2
    spmm2_kernel<<<POOL_BLOCKS, 256, 0, stream>>>(in_cnt, bucket, G2, b2, out);
}

// Round 11
// 266.509 us; speedup vs baseline: 2.2007x; 1.1781x over previous
//
#include <hip/hip_runtime.h>
#include <math.h>

#define N_NODES 50000
#define N_EDGES 800000
#define IN_FEATS 128
#define N_HIDDEN 128
#define N_CLASSES 40
#define SEQ_LEN 20
#define VOCAB 32000
#define BUCKET_CAP 64     // P(in_deg >= 64 | Poisson(16)) ~ 1e-18; guarded anyway
#define EDGE_BLOCKS 1563  // ceil(800000 / (256*2))
#define POOL_BLOCKS 12500 // 4 nodes per 256-thread block
#define K1_BLOCKS (EDGE_BLOCKS + POOL_BLOCKS)   // 14063; edge blocks at b%9==0

// prep kernel block ranges
#define ZERO_BLOCKS 98    // 25088 int4 = 401408 B (in_cnt + out_cnt)
#define EMB_BLOCKS 4000   // 32000*128/4 ushort4 conversions
#define W1P_BLOCKS 64     // 16384 packed W1 elements
#define PREP_BLOCKS (ZERO_BLOCKS + EMB_BLOCKS + W1P_BLOCKS)

typedef __attribute__((ext_vector_type(8))) short bf16x8;   // 8 bf16 (4 VGPRs)
typedef __attribute__((ext_vector_type(4))) float f32x4;    // MFMA accumulator

// bf16 helpers (RNE)
__device__ inline unsigned short f2bf(float x) {
    union { float f; unsigned int u; } v; v.f = x;
    unsigned int r = v.u + 0x7FFF + ((v.u >> 16) & 1);
    return (unsigned short)(r >> 16);
}
__device__ inline float bf2f(unsigned short b) {
    union { float f; unsigned int u; } v; v.u = ((unsigned int)b) << 16;
    return v.f;
}

// ---------------- workspace layout (bytes) ----------------
//   in_cnt : 0         int[50000]            (zeroed by prep)
//   out_cnt: 200704    int[50000]            (zeroed by prep)
//   bucket : 401408    int[50000*64]   12.8 MB
//   h0bf   : 13201408  ushort[50000*128] 12.8 MB (bf16)
//   W1p    : 26001408  ushort[128*128]   32 KB (bf16, MFMA-frag-packed)
//   G1     : 26034176  ushort[50000*128] 12.8 MB (bf16)
//     emb_bf OVERLAYS G1 (8.19 MB): dead after build_pool; gemm1 writes G1 after.
//   G2     : 38834176  ushort[50000*40]   4.0 MB (bf16)   total ~42.8 MB

// ===== prep: zero counters ∥ emb f32->bf16 ∥ pack W1 into MFMA B-frag layout.
// W1p[tile*512 + lane*8 + j] = bf16(W1[k][n]),  tile = nt*4+kb,
//   k = kb*32 + (lane>>4)*8 + j,  n = nt*16 + (lane&15)
__global__ __launch_bounds__(256) void prep_kernel(
        int4* __restrict__ zero_region, const float4* __restrict__ emb4,
        ushort4* __restrict__ emb_bf4, const float* __restrict__ W1,
        unsigned short* __restrict__ W1p) {
    int b = blockIdx.x;
    int t = threadIdx.x;
    if (b < ZERO_BLOCKS) {
        int i = b * 256 + t;
        if (i < 25088) zero_region[i] = make_int4(0, 0, 0, 0);
    } else if (b < ZERO_BLOCKS + EMB_BLOCKS) {
        int i = (b - ZERO_BLOCKS) * 256 + t;   // exactly 1024000
        float4 x = emb4[i];
        ushort4 o = {f2bf(x.x), f2bf(x.y), f2bf(x.z), f2bf(x.w)};
        emb_bf4[i] = o;
    } else {
        int i = (b - ZERO_BLOCKS - EMB_BLOCKS) * 256 + t;  // exactly 16384
        int tile = i >> 9, rem = i & 511;
        int ln = rem >> 3, j = rem & 7;
        int nt = tile >> 2, kb = tile & 3;
        int k = kb * 32 + ((ln >> 4) << 3) + j;
        int n = nt * 16 + (ln & 15);
        W1p[i] = f2bf(W1[k * 128 + n]);
    }
}

// ===== K1: single-pass bucket-CSC build + out-degree histogram (fabric-atomic)
// interleaved (b%9==0) with embedding mean-pool (bf16 gather -> bf16 h0).
__global__ __launch_bounds__(256) void build_pool_kernel(
        const int* __restrict__ src, const int* __restrict__ dst,
        int* __restrict__ in_cnt, int* __restrict__ out_cnt, int* __restrict__ bucket,
        const int* __restrict__ feats, const unsigned short* __restrict__ emb_bf,
        unsigned short* __restrict__ h0bf) {
    int b = blockIdx.x;
    int t = threadIdx.x;
    if (b % 9 == 0) {
        // ---- edge path: 2 edges/thread, vectorized int2 loads
        int gid = (b / 9) * 256 + t;
        if (gid < N_EDGES / 2) {
            int2 s2 = ((const int2*)src)[gid];
            int2 d2 = ((const int2*)dst)[gid];
            int p0 = atomicAdd(&in_cnt[d2.x], 1);
            if (p0 < BUCKET_CAP) bucket[d2.x * BUCKET_CAP + p0] = s2.x;
            atomicAdd(&out_cnt[s2.x], 1);
            int p1 = atomicAdd(&in_cnt[d2.y], 1);
            if (p1 < BUCKET_CAP) bucket[d2.y * BUCKET_CAP + p1] = s2.y;
            atomicAdd(&out_cnt[s2.y], 1);
        }
    } else {
        // ---- pool path: 4 nodes/block, 64 lanes span 128 feats via ushort2
        int pb = b - b / 9 - 1;
        int v = pb * 4 + (t >> 6);
        int lane = t & 63;
        const int* tk = feats + v * SEQ_LEN;
        const ushort2* ev = (const ushort2*)emb_bf;
        float a0 = 0.f, a1 = 0.f;
        int cnt = 0;
        #pragma unroll
        for (int s = 0; s < SEQ_LEN; ++s) {
            int tok = tk[s];
            cnt += (tok != 0);
            ushort2 g = ev[tok * 64 + lane];   // pad row 0 is all-zero
            a0 += bf2f(g.x);
            a1 += bf2f(g.y);
        }
        float sc = 1.f / (float)max(cnt, 1);   // rout folded into gemm1 epilogue
        ushort2 o = {f2bf(a0 * sc), f2bf(a1 * sc)};
        ((ushort2*)h0bf)[v * 64 + lane] = o;
    }
}

// ===== gemm1 via MFMA bf16: G1 = (rout ⊙ h0) @ W1.
// 4 waves/block; each wave computes a 16-row x 128-col strip; no LDS.
// A-frag: A[m=lane&15][k=kb*32+quad*8+j] directly from row-major h0bf (16B loads).
// B-frag: from W1p packed layout. C/D: col=lane&15, row=quad*4+reg (verified m89/m91).
__global__ __launch_bounds__(256) void gemm1_mfma(
        const unsigned short* __restrict__ h0bf, const unsigned short* __restrict__ W1p,
        const int* __restrict__ out_cnt, unsigned short* __restrict__ G1) {
    const int wave = threadIdx.x >> 6, lane = threadIdx.x & 63;
    const int quad = lane >> 4, m = lane & 15;
    const int row0 = blockIdx.x * 64 + wave * 16;
    const int arow = min(row0 + m, N_NODES - 1);
    const unsigned short* ap = h0bf + arow * 128 + quad * 8;
    bf16x8 a0 = *(const bf16x8*)(ap + 0);
    bf16x8 a1 = *(const bf16x8*)(ap + 32);
    bf16x8 a2 = *(const bf16x8*)(ap + 64);
    bf16x8 a3 = *(const bf16x8*)(ap + 96);
    const int rbase = row0 + quad * 4;
    float rout[4];
    #pragma unroll
    for (int r = 0; r < 4; ++r) {
        int rr = min(rbase + r, N_NODES - 1);
        rout[r] = 1.f / sqrtf(fmaxf((float)out_cnt[rr], 1.f));
    }
    #pragma unroll
    for (int nt = 0; nt < 8; ++nt) {
        const unsigned short* wp = W1p + (nt * 4) * 512 + lane * 8;
        bf16x8 b0 = *(const bf16x8*)(wp + 0 * 512);
        bf16x8 b1 = *(const bf16x8*)(wp + 1 * 512);
        bf16x8 b2 = *(const bf16x8*)(wp + 2 * 512);
        bf16x8 b3 = *(const bf16x8*)(wp + 3 * 512);
        f32x4 acc = {0.f, 0.f, 0.f, 0.f};
        acc = __builtin_amdgcn_mfma_f32_16x16x32_bf16(a0, b0, acc, 0, 0, 0);
        acc = __builtin_amdgcn_mfma_f32_16x16x32_bf16(a1, b1, acc, 0, 0, 0);
        acc = __builtin_amdgcn_mfma_f32_16x16x32_bf16(a2, b2, acc, 0, 0, 0);
        acc = __builtin_amdgcn_mfma_f32_16x16x32_bf16(a3, b3, acc, 0, 0, 0);
        #pragma unroll
        for (int r = 0; r < 4; ++r) {
            int row = rbase + r;
            if (row < N_NODES)
                G1[row * 128 + nt * 16 + m] = f2bf(acc[r] * rout[r]);
        }
    }
}

// ===== spmm1 + gemm2 fused: 4 nodes/block, ushort2 gathers; h1 (LDS) -> G2
__global__ __launch_bounds__(256) void spmm1g2_kernel(
        const int* __restrict__ in_cnt, const int* __restrict__ out_cnt,
        const int* __restrict__ bucket, const unsigned short* __restrict__ G,
        const float* __restrict__ b1, const float* __restrict__ W2,
        unsigned short* __restrict__ G2) {
    __shared__ float h1s[4][128];
    int t = threadIdx.x;
    int node = t >> 6, lane = t & 63;
    int v = blockIdx.x * 4 + node;
    int cnt = in_cnt[v];
    int n = min(cnt, BUCKET_CAP);
    const int* bk = bucket + v * BUCKET_CAP;
    const ushort2* Gv = (const ushort2*)G;
    float a0 = 0.f, a1 = 0.f;
    int e = 0;
    for (; e + 8 <= n; e += 8) {
        int u0 = bk[e + 0], u1 = bk[e + 1], u2 = bk[e + 2], u3 = bk[e + 3];
        int u4 = bk[e + 4], u5 = bk[e + 5], u6 = bk[e + 6], u7 = bk[e + 7];
        ushort2 g0 = Gv[u0 * 64 + lane];
        ushort2 g1 = Gv[u1 * 64 + lane];
        ushort2 g2 = Gv[u2 * 64 + lane];
        ushort2 g3 = Gv[u3 * 64 + lane];
        ushort2 g4 = Gv[u4 * 64 + lane];
        ushort2 g5 = Gv[u5 * 64 + lane];
        ushort2 g6 = Gv[u6 * 64 + lane];
        ushort2 g7 = Gv[u7 * 64 + lane];
        a0 += ((bf2f(g0.x) + bf2f(g1.x)) + (bf2f(g2.x) + bf2f(g3.x))) +
              ((bf2f(g4.x) + bf2f(g5.x)) + (bf2f(g6.x) + bf2f(g7.x)));
        a1 += ((bf2f(g0.y) + bf2f(g1.y)) + (bf2f(g2.y) + bf2f(g3.y))) +
              ((bf2f(g4.y) + bf2f(g5.y)) + (bf2f(g6.y) + bf2f(g7.y)));
    }
    if (e + 4 <= n) {
        int u0 = bk[e + 0], u1 = bk[e + 1], u2 = bk[e + 2], u3 = bk[e + 3];
        ushort2 g0 = Gv[u0 * 64 + lane];
        ushort2 g1 = Gv[u1 * 64 + lane];
        ushort2 g2 = Gv[u2 * 64 + lane];
        ushort2 g3 = Gv[u3 * 64 + lane];
        a0 += (bf2f(g0.x) + bf2f(g1.x)) + (bf2f(g2.x) + bf2f(g3.x));
        a1 += (bf2f(g0.y) + bf2f(g1.y)) + (bf2f(g2.y) + bf2f(g3.y));
        e += 4;
    }
    for (; e < n; ++e) {
        ushort2 g = Gv[bk[e] * 64 + lane];
        a0 += bf2f(g.x);
        a1 += bf2f(g.y);
    }
    float rin = 1.f / sqrtf(fmaxf((float)cnt, 1.f));
    float rout = 1.f / sqrtf(fmaxf((float)out_cnt[v], 1.f));
    float2 bb = ((const float2*)b1)[lane];
    h1s[node][2 * lane + 0] = fmaxf(a0 * rin + bb.x, 0.f) * rout;
    h1s[node][2 * lane + 1] = fmaxf(a1 * rin + bb.y, 0.f) * rout;
    __syncthreads();
    if (lane < N_CLASSES) {
        const float* hn = h1s[node];
        float s0 = 0.f, s1 = 0.f, s2 = 0.f, s3 = 0.f;
        #pragma unroll 8
        for (int k = 0; k < 128; k += 4) {
            s0 += hn[k + 0] * W2[(k + 0) * N_CLASSES + lane];
            s1 += hn[k + 1] * W2[(k + 1) * N_CLASSES + lane];
            s2 += hn[k + 2] * W2[(k + 2) * N_CLASSES + lane];
            s3 += hn[k + 3] * W2[(k + 3) * N_CLASSES + lane];
        }
        G2[v * N_CLASSES + lane] = f2bf((s0 + s1) + (s2 + s3));
    }
}

// layer-2 aggregate (bf16 bucket-gather from 4 MB L2-friendly G2) + epilogue
__global__ __launch_bounds__(256) void spmm2_kernel(
        const int* __restrict__ in_cnt, const int* __restrict__ bucket,
        const unsigned short* __restrict__ G2, const float* __restrict__ b2,
        float* __restrict__ out) {
    int t = threadIdx.x;
    int node = t >> 6, f = t & 63;
    int v = blockIdx.x * 4 + node;
    int cnt = in_cnt[v];
    int n = min(cnt, BUCKET_CAP);
    const int* bk = bucket + v * BUCKET_CAP;
    if (f < N_CLASSES) {
        float acc = 0.f;
        int e = 0;
        for (; e + 8 <= n; e += 8) {
            int u0 = bk[e + 0], u1 = bk[e + 1], u2 = bk[e + 2], u3 = bk[e + 3];
            int u4 = bk[e + 4], u5 = bk[e + 5], u6 = bk[e + 6], u7 = bk[e + 7];
            acc += ((bf2f(G2[u0 * N_CLASSES + f]) + bf2f(G2[u1 * N_CLASSES + f])) +
                    (bf2f(G2[u2 * N_CLASSES + f]) + bf2f(G2[u3 * N_CLASSES + f]))) +
                   ((bf2f(G2[u4 * N_CLASSES + f]) + bf2f(G2[u5 * N_CLASSES + f])) +
                    (bf2f(G2[u6 * N_CLASSES + f]) + bf2f(G2[u7 * N_CLASSES + f])));
        }
        if (e + 4 <= n) {
            int u0 = bk[e + 0], u1 = bk[e + 1], u2 = bk[e + 2], u3 = bk[e + 3];
            acc += (bf2f(G2[u0 * N_CLASSES + f]) + bf2f(G2[u1 * N_CLASSES + f])) +
                   (bf2f(G2[u2 * N_CLASSES + f]) + bf2f(G2[u3 * N_CLASSES + f]));
            e += 4;
        }
        for (; e < n; ++e) acc += bf2f(G2[bk[e] * N_CLASSES + f]);
        float rin = 1.f / sqrtf(fmaxf((float)cnt, 1.f));
        out[v * N_CLASSES + f] = acc * rin + b2[f];
    }
}

extern "C" void kernel_launch(void* const* d_in, const int* in_sizes, int n_in,
                              void* d_out, int out_size, void* d_ws, size_t ws_size,
                              hipStream_t stream) {
    const int*   feats = (const int*)d_in[0];
    const int*   src   = (const int*)d_in[1];
    const int*   dst   = (const int*)d_in[2];
    const float* emb   = (const float*)d_in[3];
    const float* W1    = (const float*)d_in[4];
    const float* b1    = (const float*)d_in[5];
    const float* W2    = (const float*)d_in[6];
    const float* b2    = (const float*)d_in[7];
    float* out = (float*)d_out;

    char* w = (char*)d_ws;
    int*   in_cnt  = (int*)(w + 0);
    int*   out_cnt = (int*)(w + 200704);
    int*   bucket  = (int*)(w + 401408);
    unsigned short* h0bf   = (unsigned short*)(w + 13201408);
    unsigned short* W1p    = (unsigned short*)(w + 26001408);
    unsigned short* G1     = (unsigned short*)(w + 26034176);
    unsigned short* emb_bf = (unsigned short*)(w + 26034176);  // overlays G1 (dead before gemm1)
    unsigned short* G2     = (unsigned short*)(w + 38834176);

    // 1) prep: zero counters ∥ emb->bf16 ∥ W1 frag-pack
    prep_kernel<<<PREP_BLOCKS, 256, 0, stream>>>(
        (int4*)w, (const float4*)emb, (ushort4*)emb_bf, W1, W1p);
    // 2) K1: bucket-CSC build + out-degree (atomics) interleaved with mean-pool
    build_pool_kernel<<<K1_BLOCKS, 256, 0, stream>>>(
        src, dst, in_cnt, out_cnt, bucket, feats, emb_bf, h0bf);
    // 3) G1 = (rout ⊙ h0) @ W1 via MFMA bf16 (overwrites emb_bf region)
    gemm1_mfma<<<782, 256, 0, stream>>>(h0bf, W1p, out_cnt, G1);
    // 4) spmm1 + gemm2 fused -> G2 (bf16, 4 MB)
    spmm1g2_kernel<<<POOL_BLOCKS, 256, 0, stream>>>(in_cnt, out_cnt, bucket, G1, b1, W2, G2);
    // 5) out = agg(G2)*rin + b2
    spmm2_kernel<<<POOL_BLOCKS, 256, 0, stream>>>(in_cnt, bucket, G2, b2, out);
}

// Round 14
// 255.196 us; speedup vs baseline: 2.2983x; 1.0443x over previous
//
#include <hip/hip_runtime.h>
#include <math.h>

#define N_NODES 50000
#define N_EDGES 800000
#define IN_FEATS 128
#define N_HIDDEN 128
#define N_CLASSES 40
#define SEQ_LEN 20
#define VOCAB 32000
#define BUCKET_CAP 64     // P(in_deg >= 64 | Poisson(16)) ~ 1e-18; guarded anyway
#define EDGE_BLOCKS 1563  // ceil(800000 / (256*2))
#define POOL_BLOCKS 12500 // 4 nodes per 256-thread block
#define K1_BLOCKS (EDGE_BLOCKS + POOL_BLOCKS)   // 14063; edge blocks at b%9==0

// prep kernel block ranges
#define ZERO_BLOCKS 98    // 25088 int4 = 401408 B (in_cnt + out_cnt)
#define EMB_BLOCKS 4000   // 32000*128/4 ushort4 conversions
#define W1P_BLOCKS 64     // 16384 packed W1 elements
#define PREP_BLOCKS (ZERO_BLOCKS + EMB_BLOCKS + W1P_BLOCKS)

typedef __attribute__((ext_vector_type(8))) short bf16x8;   // 8 bf16 (4 VGPRs)
typedef __attribute__((ext_vector_type(4))) float f32x4;    // MFMA accumulator

// bf16 helpers (RNE)
__device__ inline unsigned short f2bf(float x) {
    union { float f; unsigned int u; } v; v.f = x;
    unsigned int r = v.u + 0x7FFF + ((v.u >> 16) & 1);
    return (unsigned short)(r >> 16);
}
__device__ inline float bf2f(unsigned short b) {
    union { float f; unsigned int u; } v; v.u = ((unsigned int)b) << 16;
    return v.f;
}

// ---------------- workspace layout (bytes) ----------------
//   in_cnt : 0         int[50000]            (zeroed by prep)
//   out_cnt: 200704    int[50000]            (zeroed by prep)
//   bucket : 401408    int[50000*64]   12.8 MB
//   h0bf   : 13201408  ushort[50000*128] 12.8 MB (bf16)
//   W1p    : 26001408  ushort[128*128]   32 KB (bf16, MFMA-frag-packed)
//   G1     : 26034176  ushort[50000*128] 12.8 MB (bf16)
//     emb_bf OVERLAYS G1 (8.19 MB): dead after build_pool; gemm1 writes G1 after.
//   G2     : 38834176  ushort[50000*40]   4.0 MB (bf16)   total ~42.8 MB

// ===== prep: zero counters ∥ emb f32->bf16 ∥ pack W1 into MFMA B-frag layout.
__global__ __launch_bounds__(256) void prep_kernel(
        int4* __restrict__ zero_region, const float4* __restrict__ emb4,
        ushort4* __restrict__ emb_bf4, const float* __restrict__ W1,
        unsigned short* __restrict__ W1p) {
    int b = blockIdx.x;
    int t = threadIdx.x;
    if (b < ZERO_BLOCKS) {
        int i = b * 256 + t;
        if (i < 25088) zero_region[i] = make_int4(0, 0, 0, 0);
    } else if (b < ZERO_BLOCKS + EMB_BLOCKS) {
        int i = (b - ZERO_BLOCKS) * 256 + t;   // exactly 1024000
        float4 x = emb4[i];
        ushort4 o = {f2bf(x.x), f2bf(x.y), f2bf(x.z), f2bf(x.w)};
        emb_bf4[i] = o;
    } else {
        int i = (b - ZERO_BLOCKS - EMB_BLOCKS) * 256 + t;  // exactly 16384
        int tile = i >> 9, rem = i & 511;
        int ln = rem >> 3, j = rem & 7;
        int nt = tile >> 2, kb = tile & 3;
        int k = kb * 32 + ((ln >> 4) << 3) + j;
        int n = nt * 16 + (ln & 15);
        W1p[i] = f2bf(W1[k * 128 + n]);
    }
}

// ===== K1: single-pass bucket-CSC build + out-degree histogram (fabric-atomic)
// interleaved (b%9==0) with embedding mean-pool (bf16 gather -> bf16 h0).
__global__ __launch_bounds__(256) void build_pool_kernel(
        const int* __restrict__ src, const int* __restrict__ dst,
        int* __restrict__ in_cnt, int* __restrict__ out_cnt, int* __restrict__ bucket,
        const int* __restrict__ feats, const unsigned short* __restrict__ emb_bf,
        unsigned short* __restrict__ h0bf) {
    int b = blockIdx.x;
    int t = threadIdx.x;
    if (b % 9 == 0) {
        // ---- edge path: 2 edges/thread, vectorized int2 loads
        int gid = (b / 9) * 256 + t;
        if (gid < N_EDGES / 2) {
            int2 s2 = ((const int2*)src)[gid];
            int2 d2 = ((const int2*)dst)[gid];
            int p0 = atomicAdd(&in_cnt[d2.x], 1);
            if (p0 < BUCKET_CAP) bucket[d2.x * BUCKET_CAP + p0] = s2.x;
            atomicAdd(&out_cnt[s2.x], 1);
            int p1 = atomicAdd(&in_cnt[d2.y], 1);
            if (p1 < BUCKET_CAP) bucket[d2.y * BUCKET_CAP + p1] = s2.y;
            atomicAdd(&out_cnt[s2.y], 1);
        }
    } else {
        // ---- pool path: 4 nodes/block, 64 lanes span 128 feats via ushort2
        int pb = b - b / 9 - 1;
        int v = pb * 4 + (t >> 6);
        int lane = t & 63;
        const int* tk = feats + v * SEQ_LEN;
        const ushort2* ev = (const ushort2*)emb_bf;
        float a0 = 0.f, a1 = 0.f;
        int cnt = 0;
        #pragma unroll
        for (int s = 0; s < SEQ_LEN; ++s) {
            int tok = tk[s];
            cnt += (tok != 0);
            ushort2 g = ev[tok * 64 + lane];   // pad row 0 is all-zero
            a0 += bf2f(g.x);
            a1 += bf2f(g.y);
        }
        float sc = 1.f / (float)max(cnt, 1);   // rout folded into gemm1 epilogue
        ushort2 o = {f2bf(a0 * sc), f2bf(a1 * sc)};
        ((ushort2*)h0bf)[v * 64 + lane] = o;
    }
}

// ===== gemm1 via MFMA bf16: G1 = (rout ⊙ h0) @ W1.  (verified R11: ~10 µs)
__global__ __launch_bounds__(256) void gemm1_mfma(
        const unsigned short* __restrict__ h0bf, const unsigned short* __restrict__ W1p,
        const int* __restrict__ out_cnt, unsigned short* __restrict__ G1) {
    const int wave = threadIdx.x >> 6, lane = threadIdx.x & 63;
    const int quad = lane >> 4, m = lane & 15;
    const int row0 = blockIdx.x * 64 + wave * 16;
    const int arow = min(row0 + m, N_NODES - 1);
    const unsigned short* ap = h0bf + arow * 128 + quad * 8;
    bf16x8 a0 = *(const bf16x8*)(ap + 0);
    bf16x8 a1 = *(const bf16x8*)(ap + 32);
    bf16x8 a2 = *(const bf16x8*)(ap + 64);
    bf16x8 a3 = *(const bf16x8*)(ap + 96);
    const int rbase = row0 + quad * 4;
    float rout[4];
    #pragma unroll
    for (int r = 0; r < 4; ++r) {
        int rr = min(rbase + r, N_NODES - 1);
        rout[r] = 1.f / sqrtf(fmaxf((float)out_cnt[rr], 1.f));
    }
    #pragma unroll
    for (int nt = 0; nt < 8; ++nt) {
        const unsigned short* wp = W1p + (nt * 4) * 512 + lane * 8;
        bf16x8 b0 = *(const bf16x8*)(wp + 0 * 512);
        bf16x8 b1 = *(const bf16x8*)(wp + 1 * 512);
        bf16x8 b2 = *(const bf16x8*)(wp + 2 * 512);
        bf16x8 b3 = *(const bf16x8*)(wp + 3 * 512);
        f32x4 acc = {0.f, 0.f, 0.f, 0.f};
        acc = __builtin_amdgcn_mfma_f32_16x16x32_bf16(a0, b0, acc, 0, 0, 0);
        acc = __builtin_amdgcn_mfma_f32_16x16x32_bf16(a1, b1, acc, 0, 0, 0);
        acc = __builtin_amdgcn_mfma_f32_16x16x32_bf16(a2, b2, acc, 0, 0, 0);
        acc = __builtin_amdgcn_mfma_f32_16x16x32_bf16(a3, b3, acc, 0, 0, 0);
        #pragma unroll
        for (int r = 0; r < 4; ++r) {
            int row = rbase + r;
            if (row < N_NODES)
                G1[row * 128 + nt * 16 + m] = f2bf(acc[r] * rout[r]);
        }
    }
}

// ===== spmm1 + gemm2 fused: bucket indices staged in LDS (kills per-lane
// redundant VMEM index loads); 4 nodes/block, ushort2 gathers; h1 (LDS) -> G2
__global__ __launch_bounds__(256) void spmm1g2_kernel(
        const int* __restrict__ in_cnt, const int* __restrict__ out_cnt,
        const int* __restrict__ bucket, const unsigned short* __restrict__ G,
        const float* __restrict__ b1, const float* __restrict__ W2,
        unsigned short* __restrict__ G2) {
    __shared__ int idxs[256];
    __shared__ float h1s[4][128];
    int t = threadIdx.x;
    int node = t >> 6, lane = t & 63;
    int v = blockIdx.x * 4 + node;
    // stage the 4 nodes' bucket rows (contiguous 1 KB) into LDS, coalesced
    idxs[t] = bucket[blockIdx.x * 256 + t];
    __syncthreads();
    int cnt = in_cnt[v];
    int n = min(cnt, BUCKET_CAP);
    const int* bk = &idxs[node * BUCKET_CAP];
    const ushort2* Gv = (const ushort2*)G;
    float a0 = 0.f, a1 = 0.f;
    int e = 0;
    for (; e + 8 <= n; e += 8) {
        int u0 = bk[e + 0], u1 = bk[e + 1], u2 = bk[e + 2], u3 = bk[e + 3];
        int u4 = bk[e + 4], u5 = bk[e + 5], u6 = bk[e + 6], u7 = bk[e + 7];
        ushort2 g0 = Gv[u0 * 64 + lane];
        ushort2 g1 = Gv[u1 * 64 + lane];
        ushort2 g2 = Gv[u2 * 64 + lane];
        ushort2 g3 = Gv[u3 * 64 + lane];
        ushort2 g4 = Gv[u4 * 64 + lane];
        ushort2 g5 = Gv[u5 * 64 + lane];
        ushort2 g6 = Gv[u6 * 64 + lane];
        ushort2 g7 = Gv[u7 * 64 + lane];
        a0 += ((bf2f(g0.x) + bf2f(g1.x)) + (bf2f(g2.x) + bf2f(g3.x))) +
              ((bf2f(g4.x) + bf2f(g5.x)) + (bf2f(g6.x) + bf2f(g7.x)));
        a1 += ((bf2f(g0.y) + bf2f(g1.y)) + (bf2f(g2.y) + bf2f(g3.y))) +
              ((bf2f(g4.y) + bf2f(g5.y)) + (bf2f(g6.y) + bf2f(g7.y)));
    }
    if (e + 4 <= n) {
        int u0 = bk[e + 0], u1 = bk[e + 1], u2 = bk[e + 2], u3 = bk[e + 3];
        ushort2 g0 = Gv[u0 * 64 + lane];
        ushort2 g1 = Gv[u1 * 64 + lane];
        ushort2 g2 = Gv[u2 * 64 + lane];
        ushort2 g3 = Gv[u3 * 64 + lane];
        a0 += (bf2f(g0.x) + bf2f(g1.x)) + (bf2f(g2.x) + bf2f(g3.x));
        a1 += (bf2f(g0.y) + bf2f(g1.y)) + (bf2f(g2.y) + bf2f(g3.y));
        e += 4;
    }
    for (; e < n; ++e) {
        ushort2 g = Gv[bk[e] * 64 + lane];
        a0 += bf2f(g.x);
        a1 += bf2f(g.y);
    }
    float rin = 1.f / sqrtf(fmaxf((float)cnt, 1.f));
    float rout = 1.f / sqrtf(fmaxf((float)out_cnt[v], 1.f));
    float2 bb = ((const float2*)b1)[lane];
    h1s[node][2 * lane + 0] = fmaxf(a0 * rin + bb.x, 0.f) * rout;
    h1s[node][2 * lane + 1] = fmaxf(a1 * rin + bb.y, 0.f) * rout;
    __syncthreads();
    if (lane < N_CLASSES) {
        const float* hn = h1s[node];
        float s0 = 0.f, s1 = 0.f, s2 = 0.f, s3 = 0.f;
        #pragma unroll 8
        for (int k = 0; k < 128; k += 4) {
            s0 += hn[k + 0] * W2[(k + 0) * N_CLASSES + lane];
            s1 += hn[k + 1] * W2[(k + 1) * N_CLASSES + lane];
            s2 += hn[k + 2] * W2[(k + 2) * N_CLASSES + lane];
            s3 += hn[k + 3] * W2[(k + 3) * N_CLASSES + lane];
        }
        G2[v * N_CLASSES + lane] = f2bf((s0 + s1) + (s2 + s3));
    }
}

// layer-2 aggregate (bf16 bucket-gather, LDS-staged indices) + epilogue
__global__ __launch_bounds__(256) void spmm2_kernel(
        const int* __restrict__ in_cnt, const int* __restrict__ bucket,
        const unsigned short* __restrict__ G2, const float* __restrict__ b2,
        float* __restrict__ out) {
    __shared__ int idxs[256];
    int t = threadIdx.x;
    int node = t >> 6, f = t & 63;
    int v = blockIdx.x * 4 + node;
    idxs[t] = bucket[blockIdx.x * 256 + t];
    __syncthreads();
    int cnt = in_cnt[v];
    int n = min(cnt, BUCKET_CAP);
    const int* bk = &idxs[node * BUCKET_CAP];
    if (f < N_CLASSES) {
        float acc = 0.f;
        int e = 0;
        for (; e + 8 <= n; e += 8) {
            int u0 = bk[e + 0], u1 = bk[e + 1], u2 = bk[e + 2], u3 = bk[e + 3];
            int u4 = bk[e + 4], u5 = bk[e + 5], u6 = bk[e + 6], u7 = bk[e + 7];
            acc += ((bf2f(G2[u0 * N_CLASSES + f]) + bf2f(G2[u1 * N_CLASSES + f])) +
                    (bf2f(G2[u2 * N_CLASSES + f]) + bf2f(G2[u3 * N_CLASSES + f]))) +
                   ((bf2f(G2[u4 * N_CLASSES + f]) + bf2f(G2[u5 * N_CLASSES + f])) +
                    (bf2f(G2[u6 * N_CLASSES + f]) + bf2f(G2[u7 * N_CLASSES + f])));
        }
        if (e + 4 <= n) {
            int u0 = bk[e + 0], u1 = bk[e + 1], u2 = bk[e + 2], u3 = bk[e + 3];
            acc += (bf2f(G2[u0 * N_CLASSES + f]) + bf2f(G2[u1 * N_CLASSES + f])) +
                   (bf2f(G2[u2 * N_CLASSES + f]) + bf2f(G2[u3 * N_CLASSES + f]));
            e += 4;
        }
        for (; e < n; ++e) acc += bf2f(G2[bk[e] * N_CLASSES + f]);
        float rin = 1.f / sqrtf(fmaxf((float)cnt, 1.f));
        out[v * N_CLASSES + f] = acc * rin + b2[f];
    }
}

extern "C" void kernel_launch(void* const* d_in, const int* in_sizes, int n_in,
                              void* d_out, int out_size, void* d_ws, size_t ws_size,
                              hipStream_t stream) {
    const int*   feats = (const int*)d_in[0];
    const int*   src   = (const int*)d_in[1];
    const int*   dst   = (const int*)d_in[2];
    const float* emb   = (const float*)d_in[3];
    const float* W1    = (const float*)d_in[4];
    const float* b1    = (const float*)d_in[5];
    const float* W2    = (const float*)d_in[6];
    const float* b2    = (const float*)d_in[7];
    float* out = (float*)d_out;

    char* w = (char*)d_ws;
    int*   in_cnt  = (int*)(w + 0);
    int*   out_cnt = (int*)(w + 200704);
    int*   bucket  = (int*)(w + 401408);
    unsigned short* h0bf   = (unsigned short*)(w + 13201408);
    unsigned short* W1p    = (unsigned short*)(w + 26001408);
    unsigned short* G1     = (unsigned short*)(w + 26034176);
    unsigned short* emb_bf = (unsigned short*)(w + 26034176);  // overlays G1 (dead before gemm1)
    unsigned short* G2     = (unsigned short*)(w + 38834176);

    // 1) prep: zero counters ∥ emb->bf16 ∥ W1 frag-pack
    prep_kernel<<<PREP_BLOCKS, 256, 0, stream>>>(
        (int4*)w, (const float4*)emb, (ushort4*)emb_bf, W1, W1p);
    // 2) K1: bucket-CSC build + out-degree (atomics) interleaved with mean-pool
    build_pool_kernel<<<K1_BLOCKS, 256, 0, stream>>>(
        src, dst, in_cnt, out_cnt, bucket, feats, emb_bf, h0bf);
    // 3) G1 = (rout ⊙ h0) @ W1 via MFMA bf16 (overwrites emb_bf region)
    gemm1_mfma<<<782, 256, 0, stream>>>(h0bf, W1p, out_cnt, G1);
    // 4) spmm1 + gemm2 fused -> G2 (bf16, 4 MB)
    spmm1g2_kernel<<<POOL_BLOCKS, 256, 0, stream>>>(in_cnt, out_cnt, bucket, G1, b1, W2, G2);
    // 5) out = agg(G2)*rin + b2
    spmm2_kernel<<<POOL_BLOCKS, 256, 0, stream>>>(in_cnt, bucket, G2, b2, out);
}